// Round 2
// baseline (17671.996 us; speedup 1.0000x reference)
//
#include <hip/hip_runtime.h>
#include <math.h>

#define N 1024
#define M 2048
#define C 64
#define NB 128
#define TB 8   // N/NB

// ---------------- helpers ----------------

__device__ __forceinline__ float sqdist4(const float4 a, const float4 b){
    float dx=a.x-b.x, dy=a.y-b.y, dz=a.z-b.z, dw=a.w-b.w;
    return dx*dx+dy*dy+dz*dz+dw*dw;
}

// Generic 128x128 output tile GEMM core, 256 threads, each 8x8 micro-tile.
// A accessed [r][k] (row-major, lda). B: if bT, accessed [c][k]; else [k][c].
__device__ __forceinline__ void gemm_tile_core(const float* __restrict__ A, int lda,
                                               const float* __restrict__ B, int ldb,
                                               int klen, bool bT, float acc[8][8])
{
    __shared__ float As[32][NB+1];
    __shared__ float Bs[32][NB+1];
    int tid = threadIdx.x;
    int tx = tid & 15, ty = tid >> 4;
    int r0 = ty*8, c0 = tx*8;
    for (int k0 = 0; k0 < klen; k0 += 32){
        {   // load A tile transposed: As[k][r] = A[r][k0+k]
            int k = tid & 31, r = tid >> 5;
            for (int rr = r; rr < NB; rr += 8)
                As[k][rr] = A[(size_t)rr*lda + k0 + k];
        }
        if (bT){
            int k = tid & 31, cpos = tid >> 5;
            for (int cc = cpos; cc < NB; cc += 8)
                Bs[k][cc] = B[(size_t)cc*ldb + k0 + k];
        } else {
            int cpos = tid & 127, k = tid >> 7;
            for (int kk = k; kk < 32; kk += 2)
                Bs[kk][cpos] = B[(size_t)(k0+kk)*ldb + cpos];
        }
        __syncthreads();
        #pragma unroll 8
        for (int k = 0; k < 32; k++){
            float a[8], b[8];
            #pragma unroll
            for (int u=0;u<8;u++) a[u] = As[k][r0+u];
            #pragma unroll
            for (int v=0;v<8;v++) b[v] = Bs[k][c0+v];
            #pragma unroll
            for (int u=0;u<8;u++)
                #pragma unroll
                for (int v=0;v<8;v++)
                    acc[u][v] += a[u]*b[v];
        }
        __syncthreads();
    }
}

// ---------------- kernels ----------------

__global__ void k_init_acc(float* __restrict__ acc){
    int i = blockIdx.x*blockDim.x + threadIdx.x;
    if (i < 2*M) acc[i] = 0.0f;
}

// d2teT[i][j] = ||Xtr_i - Xte_j||^2   (N x M)
__global__ void k_build_d2te(const float* __restrict__ Xtr, const float* __restrict__ Xte,
                             float* __restrict__ d2){
    int i = blockIdx.x;
    float4 xi = ((const float4*)Xtr)[i];
    for (int j = threadIdx.x; j < M; j += blockDim.x){
        float4 xj = ((const float4*)Xte)[j];
        d2[(size_t)i*M + j] = sqdist4(xi,xj);
    }
}

// K_noisy for chain c (batch-local) into Lbuf[c] (full dense, row-major N x N)
__global__ void k_build_K(const float* __restrict__ Xtr, const float* __restrict__ ls,
                          const float* __restrict__ var, const float* __restrict__ noise,
                          float* __restrict__ Lbuf){
    int c = blockIdx.y;
    int i = blockIdx.x;
    float il2 = 1.0f/(ls[c]*ls[c]);
    float vc = var[c], nc = noise[c];
    float4 xi = ((const float4*)Xtr)[i];
    float* row = Lbuf + ((size_t)c*N + i)*N;
    for (int j = threadIdx.x; j < N; j += blockDim.x){
        float4 xj = ((const float4*)Xtr)[j];
        float d2 = sqdist4(xi,xj);
        float v = vc*__expf(-0.5f*d2*il2);
        if (j==i) v += nc;
        row[j] = v;
    }
}

// Factor 128x128 diag block (lower), then invert it in LDS; write inverse
// (lower, zero upper) to Dinv. Never writes Lbuf.
__global__ __launch_bounds__(256) void k_diag(const float* __restrict__ Lbuf,
                                              float* __restrict__ Dinv, int kb){
    __shared__ float T[NB][NB];
    int c = blockIdx.x;
    const float* A = Lbuf + (size_t)c*N*N + (size_t)kb*NB*N + kb*NB;
    int tid = threadIdx.x;
    for (int idx = tid; idx < NB*NB; idx += 256){
        int r = idx >> 7, col = idx & 127;
        T[r][col] = A[(size_t)r*N + col];
    }
    __syncthreads();
    int ty = tid >> 4, tx = tid & 15;
    // Cholesky (right-looking, rank-1 on trailing square; upper is junk but never read)
    for (int j = 0; j < NB; j++){
        if (tid == 0) T[j][j] = sqrtf(T[j][j]);
        __syncthreads();
        float invd = 1.0f / T[j][j];
        for (int i = j+1+tid; i < NB; i += 256) T[i][j] *= invd;
        __syncthreads();
        for (int i = j+1+ty; i < NB; i += 16){
            float tij = T[i][j];
            for (int k = j+1+tx; k < NB; k += 16)
                T[i][k] -= tij * T[k][j];
        }
        __syncthreads();
    }
    // in-place lower-triangular inversion: row i of X from rows <i (already X) and row i of L
    for (int i = 0; i < NB; i++){
        float inv_ii = 1.0f / T[i][i];
        float S = 0.0f;
        int j = tid;
        if (j < i){
            for (int k = j; k < i; k++) S += T[i][k] * T[k][j];
        }
        __syncthreads();
        if (j < i) T[i][j] = -inv_ii * S;
        if (tid == i) T[i][i] = inv_ii;
        __syncthreads();
    }
    float* Dv = Dinv + ((size_t)c*TB + kb)*NB*NB;
    for (int idx = tid; idx < NB*NB; idx += 256){
        int r = idx >> 7, col = idx & 127;
        Dv[idx] = (col <= r) ? T[r][col] : 0.0f;
    }
}

// panel TRSM as GEMM: L[ib,kb] = A[ib,kb] @ Dinv_kb^T   (in place)
__global__ __launch_bounds__(256) void k_panel(float* __restrict__ Lbuf,
                                               const float* __restrict__ Dinv, int kb){
    int c = blockIdx.x;
    int ib = kb + 1 + blockIdx.y;
    float* Ablk = Lbuf + (size_t)c*N*N + (size_t)ib*NB*N + kb*NB;
    const float* Dv = Dinv + ((size_t)c*TB + kb)*NB*NB;
    float acc[8][8] = {};
    gemm_tile_core(Ablk, N, Dv, NB, NB, true, acc);
    int tid=threadIdx.x, tx=tid&15, ty=tid>>4;
    for (int u=0;u<8;u++)
        for (int v=0;v<8;v++)
            Ablk[(size_t)(ty*8+u)*N + tx*8+v] = acc[u][v];
}

// trailing update: A[i,j] -= P_i @ P_j^T  for kb < j <= i
__global__ __launch_bounds__(256) void k_syrk(float* __restrict__ Lbuf, int kb){
    int c = blockIdx.x;
    int flat = blockIdx.y;
    int di = 0; while ((di+1)*(di+2)/2 <= flat) di++;
    int dj = flat - di*(di+1)/2;
    int i = kb+1+di, j = kb+1+dj;
    float* base = Lbuf + (size_t)c*N*N;
    float* Cblk = base + (size_t)i*NB*N + j*NB;
    const float* Ablk = base + (size_t)i*NB*N + kb*NB;
    const float* Bblk = base + (size_t)j*NB*N + kb*NB;
    float acc[8][8] = {};
    gemm_tile_core(Ablk, N, Bblk, N, NB, true, acc);
    int tid=threadIdx.x, tx=tid&15, ty=tid>>4;
    for (int u=0;u<8;u++)
        for (int v=0;v<8;v++)
            Cblk[(size_t)(ty*8+u)*N + tx*8+v] -= acc[u][v];
}

// write W[i,i] = Dinv_i (including zero upper) into Lbuf diag blocks
__global__ void k_write_diag(float* __restrict__ Lbuf, const float* __restrict__ Dinv){
    int c = blockIdx.x, i = blockIdx.y;
    const float* S = Dinv + ((size_t)c*TB + i)*NB*NB;
    float* Dst = Lbuf + (size_t)c*N*N + (size_t)i*NB*N + i*NB;
    for (int idx = threadIdx.x; idx < NB*NB; idx += blockDim.x){
        int r = idx>>7, col = idx&127;
        Dst[(size_t)r*N + col] = S[idx];
    }
}

// Trow[c] = L[ib, kt] block copy (original L row-block, strictly lower part)
__global__ void k_copy_row(float* __restrict__ Trow, const float* __restrict__ Lbuf, int ib){
    int c = blockIdx.x, kt = blockIdx.y;
    const float* src = Lbuf + (size_t)c*N*N + (size_t)ib*NB*N + kt*NB;
    float* dst = Trow + (size_t)c*NB*N + kt*NB;
    for (int idx = threadIdx.x; idx < NB*NB; idx += blockDim.x){
        int r = idx>>7, col = idx&127;
        dst[(size_t)r*N+col] = src[(size_t)r*N+col];
    }
}

// G = Dinv_ib @ Trow   (in place per column-tile)
__global__ __launch_bounds__(256) void k_gemmA(float* __restrict__ Trow,
                                               const float* __restrict__ Dinv, int ib){
    int c = blockIdx.x, ct = blockIdx.y;
    const float* Dv = Dinv + ((size_t)c*TB + ib)*NB*NB;
    float* Tr = Trow + (size_t)c*NB*N;
    float acc[8][8] = {};
    gemm_tile_core(Dv, NB, Tr + ct*NB, N, NB, false, acc);
    int tid=threadIdx.x, tx=tid&15, ty=tid>>4;
    for (int u=0;u<8;u++)
        for (int v=0;v<8;v++)
            Tr[(size_t)(ty*8+u)*N + ct*NB + tx*8+v] = acc[u][v];
}

// W[ib,jt] = - sum_{kt=jt..ib-1} G[:,kt] @ W[kt,jt]
__global__ __launch_bounds__(256) void k_gemmB(float* __restrict__ Lbuf,
                                               const float* __restrict__ Trow, int ib){
    int c = blockIdx.x, jt = blockIdx.y;
    const float* G = Trow + (size_t)c*NB*N;
    float* base = Lbuf + (size_t)c*N*N;
    int klen = (ib - jt)*NB;
    int k0g = jt*NB;
    float acc[8][8] = {};
    gemm_tile_core(G + k0g, N, base + (size_t)k0g*N + jt*NB, N, klen, false, acc);
    float* Cb = base + (size_t)ib*NB*N + jt*NB;
    int tid=threadIdx.x, tx=tid&15, ty=tid>>4;
    for (int u=0;u<8;u++)
        for (int v=0;v<8;v++)
            Cb[(size_t)(ty*8+u)*N + tx*8+v] = -acc[u][v];
}

// z[c] = W y  (triangular matvec, one wave per row)
__global__ void k_zvec(const float* __restrict__ Lbuf, const float* __restrict__ y,
                       float* __restrict__ z){
    int c = blockIdx.x;
    int p = blockIdx.y * 4 + (threadIdx.x >> 6);
    int lane = threadIdx.x & 63;
    const float* row = Lbuf + (size_t)c*N*N + (size_t)p*N;
    float s = 0.0f;
    for (int i = lane; i <= p; i += 64) s += row[i]*y[i];
    for (int off = 32; off; off >>= 1) s += __shfl_down(s, off);
    if (lane == 0) z[c*N + p] = s;
}

// Fused: A = Kt @ W^T tile, reduce rowwise into mean/var accumulators.
// acc_out[0..M) = mean sum, acc_out[M..2M) = var sum.
__global__ __launch_bounds__(256) void k_bigg(const float* __restrict__ Lbuf,
                                              const float* __restrict__ d2,
                                              const float* __restrict__ zbuf,
                                              const float* __restrict__ ls,
                                              const float* __restrict__ var,
                                              float* __restrict__ acc_out){
    __shared__ float As[32][NB+1];
    __shared__ float Bs[32][NB+1];
    __shared__ float red[NB][17];
    int jt = blockIdx.x, pt = blockIdx.y, c = blockIdx.z;
    int tid = threadIdx.x, tx = tid&15, ty = tid>>4;
    int r0 = ty*8, c0 = tx*8;
    float il2 = 1.0f/(ls[c]*ls[c]);
    float vc = var[c];
    const float* W = Lbuf + (size_t)c*N*N;
    int klen = (pt+1)*NB;   // W row p has support only for k <= p (triangular skip)
    float acc[8][8] = {};
    for (int k0 = 0; k0 < klen; k0 += 32){
        {   // A tile: Kt[jt*128+r][k0+k] = vc*exp(-0.5*il2*d2[k0+k][jt*128+r])
            int cpos = tid & 127, k = tid >> 7;
            for (int kk = k; kk < 32; kk += 2){
                float dv = d2[(size_t)(k0+kk)*M + jt*NB + cpos];
                As[kk][cpos] = vc * __expf(-0.5f*il2*dv);
            }
        }
        {   // B tile: W[pt*128+cc][k0+k]
            int k = tid & 31, cpos = tid >> 5;
            for (int cc = cpos; cc < NB; cc += 8)
                Bs[k][cc] = W[(size_t)(pt*NB+cc)*N + k0 + k];
        }
        __syncthreads();
        #pragma unroll 8
        for (int k = 0; k < 32; k++){
            float a[8], b[8];
            #pragma unroll
            for (int u=0;u<8;u++) a[u] = As[k][r0+u];
            #pragma unroll
            for (int v=0;v<8;v++) b[v] = Bs[k][c0+v];
            #pragma unroll
            for (int u=0;u<8;u++)
                #pragma unroll
                for (int v=0;v<8;v++)
                    acc[u][v] += a[u]*b[v];
        }
        __syncthreads();
    }
    float zv[8];
    #pragma unroll
    for (int v=0;v<8;v++) zv[v] = zbuf[c*N + pt*NB + c0 + v];
    float pv[8], pm[8];
    #pragma unroll
    for (int u=0;u<8;u++){
        float sv = 0.0f, sm = 0.0f;
        #pragma unroll
        for (int v=0;v<8;v++){ sv += acc[u][v]*acc[u][v]; sm += acc[u][v]*zv[v]; }
        pv[u] = sv; pm[u] = sm;
    }
    // reduce var across tx then atomically accumulate
    #pragma unroll
    for (int u=0;u<8;u++) red[r0+u][tx] = pv[u];
    __syncthreads();
    if (tid < NB){
        float s = 0.0f;
        for (int t=0;t<16;t++) s += red[tid][t];
        atomicAdd(&acc_out[M + jt*NB + tid], s);
    }
    __syncthreads();
    #pragma unroll
    for (int u=0;u<8;u++) red[r0+u][tx] = pm[u];
    __syncthreads();
    if (tid < NB){
        float s = 0.0f;
        for (int t=0;t<16;t++) s += red[tid][t];
        atomicAdd(&acc_out[jt*NB + tid], s);
    }
}

__global__ void k_final(const float* __restrict__ acc, float* __restrict__ out){
    int i = blockIdx.x*blockDim.x + threadIdx.x;
    if (i < 2*M) out[i] = acc[i] * (1.0f/64.0f);
}

// ---------------- launch ----------------
// Chains are independent; per-chain ws = N*N (Lbuf) + TB*NB*NB (Dinv)
//   + NB*N (Trow) + N (z) floats = 5.25 MB. Batch chains to fit ws_size.

extern "C" void kernel_launch(void* const* d_in, const int* in_sizes, int n_in,
                              void* d_out, int out_size, void* d_ws, size_t ws_size,
                              hipStream_t stream) {
    const float* Xtr = (const float*)d_in[0];
    const float* ytr = (const float*)d_in[1];
    const float* Xte = (const float*)d_in[2];
    const float* ls  = (const float*)d_in[3];
    const float* var = (const float*)d_in[4];
    const float* noi = (const float*)d_in[5];
    float* out = (float*)d_out;

    float* ws = (float*)d_ws;
    const size_t shared_fl  = (size_t)N*M + 2*M;              // d2te + acc
    const size_t perchain   = (size_t)N*N + (size_t)TB*NB*NB
                            + (size_t)NB*N + (size_t)N;       // Lbuf+Dinv+Trow+z
    size_t avail = ws_size / sizeof(float);
    if (avail < shared_fl + perchain) return;   // cannot run even 1 chain
    int Gmax = (int)((avail - shared_fl) / perchain);
    if (Gmax > C) Gmax = C;
    int nbatch = (C + Gmax - 1) / Gmax;
    int G = (C + nbatch - 1) / nbatch;          // balanced batches

    float* d2te = ws;
    float* acc  = d2te + (size_t)N*M;
    float* Lbuf = acc  + 2*M;
    float* Dinv = Lbuf + (size_t)G*N*N;
    float* Trow = Dinv + (size_t)G*TB*NB*NB;
    float* zbuf = Trow + (size_t)G*NB*N;

    k_init_acc<<<dim3((2*M+255)/256), dim3(256), 0, stream>>>(acc);
    k_build_d2te<<<dim3(N), dim3(256), 0, stream>>>(Xtr, Xte, d2te);

    for (int c0 = 0; c0 < C; c0 += G){
        int g = C - c0 < G ? C - c0 : G;

        k_build_K<<<dim3(N, g), dim3(256), 0, stream>>>(Xtr, ls+c0, var+c0, noi+c0, Lbuf);

        for (int kb = 0; kb < TB; kb++){
            k_diag<<<dim3(g), dim3(256), 0, stream>>>(Lbuf, Dinv, kb);
            int rem = TB-1-kb;
            if (rem > 0){
                k_panel<<<dim3(g, rem), dim3(256), 0, stream>>>(Lbuf, Dinv, kb);
                k_syrk<<<dim3(g, rem*(rem+1)/2), dim3(256), 0, stream>>>(Lbuf, kb);
            }
        }
        k_write_diag<<<dim3(g, TB), dim3(256), 0, stream>>>(Lbuf, Dinv);
        for (int ib = 1; ib < TB; ib++){
            k_copy_row<<<dim3(g, ib), dim3(256), 0, stream>>>(Trow, Lbuf, ib);
            k_gemmA<<<dim3(g, ib), dim3(256), 0, stream>>>(Trow, Dinv, ib);
            k_gemmB<<<dim3(g, ib), dim3(256), 0, stream>>>(Lbuf, Trow, ib);
        }
        k_zvec<<<dim3(g, N/4), dim3(256), 0, stream>>>(Lbuf, ytr, zbuf);
        k_bigg<<<dim3(M/NB, TB, g), dim3(256), 0, stream>>>(Lbuf, d2te, zbuf, ls+c0, var+c0, acc);
    }
    k_final<<<dim3((2*M+255)/256), dim3(256), 0, stream>>>(acc, out);
}

// Round 3
// 15792.003 us; speedup vs baseline: 1.1190x; 1.1190x over previous
//
#include <hip/hip_runtime.h>
#include <math.h>

#define N 1024
#define M 2048
#define C 64
#define NB 128
#define TB 8   // N/NB
#define PAD 4  // LDS row pad (floats) -> 132-float rows, 16B aligned

// ---------------- helpers ----------------

__device__ __forceinline__ float sqdist4(const float4 a, const float4 b){
    float dx=a.x-b.x, dy=a.y-b.y, dz=a.z-b.z, dw=a.w-b.w;
    return dx*dx+dy*dy+dz*dz+dw*dw;
}

// Load 32(k) x 128(c) tile from row-major S[c][k] (i.e. transposed into Ts[k][c]).
// Global: float4 along k; LDS: 4 scalar writes (4-way write conflict, rare).
__device__ __forceinline__ void load_tileT(float Ts[32][NB+PAD], const float* __restrict__ S,
                                           int lds_, int tid){
    int k4 = (tid & 7) * 4, c0 = tid >> 3;
    #pragma unroll
    for (int cc = c0; cc < NB; cc += 32){
        float4 v = *(const float4*)&S[(size_t)cc*lds_ + k4];
        Ts[k4+0][cc] = v.x; Ts[k4+1][cc] = v.y; Ts[k4+2][cc] = v.z; Ts[k4+3][cc] = v.w;
    }
}

// Load 32(k) x 128(c) tile from row-major S[k][c] straight into Ts[k][c].
// float4 both sides; conflict-free.
__device__ __forceinline__ void load_tileS(float Ts[32][NB+PAD], const float* __restrict__ S,
                                           int lds_, int tid){
    int c4 = (tid & 31) * 4, kk = tid >> 5;
    #pragma unroll
    for (int k = kk; k < 32; k += 8){
        float4 v = *(const float4*)&S[(size_t)k*lds_ + c4];
        *(float4*)&Ts[k][c4] = v;
    }
}

// 8x8 micro-tile FMA over one 32-deep k-slab.
// Rows r0..r0+7 (broadcast reads), cols ca..ca+3 and cb..cb+3 (2-way, free).
__device__ __forceinline__ void mm32(const float As[32][NB+PAD], const float Bs[32][NB+PAD],
                                     int r0, int ca, int cb, float acc[8][8]){
    #pragma unroll 8
    for (int k = 0; k < 32; k++){
        float4 a0 = *(const float4*)&As[k][r0];
        float4 a1 = *(const float4*)&As[k][r0+4];
        float4 b0 = *(const float4*)&Bs[k][ca];
        float4 b1 = *(const float4*)&Bs[k][cb];
        float a[8] = {a0.x,a0.y,a0.z,a0.w,a1.x,a1.y,a1.z,a1.w};
        float b[8] = {b0.x,b0.y,b0.z,b0.w,b1.x,b1.y,b1.z,b1.w};
        #pragma unroll
        for (int u=0;u<8;u++)
            #pragma unroll
            for (int v=0;v<8;v++)
                acc[u][v] += a[u]*b[v];
    }
}

// Full 128x128-output GEMM core. A accessed [r][k] (row-major, lda).
// B: if bT, accessed [c][k]; else [k][c].
__device__ __forceinline__ void gemm_core(const float* __restrict__ A, int lda,
                                          const float* __restrict__ B, int ldb,
                                          int klen, bool bT, float acc[8][8],
                                          float As[32][NB+PAD], float Bs[32][NB+PAD])
{
    int tid = threadIdx.x;
    int r0 = (tid >> 4) * 8, ca = (tid & 15) * 4, cb = 64 + ca;
    for (int k0 = 0; k0 < klen; k0 += 32){
        load_tileT(As, A + k0, lda, tid);
        if (bT) load_tileT(Bs, B + k0, ldb, tid);
        else    load_tileS(Bs, B + (size_t)k0*ldb, ldb, tid);
        __syncthreads();
        mm32(As, Bs, r0, ca, cb, acc);
        __syncthreads();
    }
}

__device__ __forceinline__ void store_acc(float* __restrict__ Cp, int ldc,
                                          const float acc[8][8], float sgn){
    int tid = threadIdx.x;
    int r0 = (tid >> 4) * 8, ca = (tid & 15) * 4, cb = 64 + ca;
    #pragma unroll
    for (int u=0;u<8;u++){
        float4 v0 = make_float4(sgn*acc[u][0], sgn*acc[u][1], sgn*acc[u][2], sgn*acc[u][3]);
        float4 v1 = make_float4(sgn*acc[u][4], sgn*acc[u][5], sgn*acc[u][6], sgn*acc[u][7]);
        *(float4*)&Cp[(size_t)(r0+u)*ldc + ca] = v0;
        *(float4*)&Cp[(size_t)(r0+u)*ldc + cb] = v1;
    }
}

// ---------------- kernels ----------------

__global__ void k_init_acc(float* __restrict__ acc){
    int i = blockIdx.x*blockDim.x + threadIdx.x;
    if (i < 2*M) acc[i] = 0.0f;
}

// d2teT[i][j] = ||Xtr_i - Xte_j||^2   (N x M)
__global__ void k_build_d2te(const float* __restrict__ Xtr, const float* __restrict__ Xte,
                             float* __restrict__ d2){
    int i = blockIdx.x;
    float4 xi = ((const float4*)Xtr)[i];
    for (int j = threadIdx.x; j < M; j += blockDim.x){
        float4 xj = ((const float4*)Xte)[j];
        d2[(size_t)i*M + j] = sqdist4(xi,xj);
    }
}

// K_noisy for chain c (batch-local) into Lbuf[c] (full dense, row-major N x N)
__global__ void k_build_K(const float* __restrict__ Xtr, const float* __restrict__ ls,
                          const float* __restrict__ var, const float* __restrict__ noise,
                          float* __restrict__ Lbuf){
    int c = blockIdx.y;
    int i = blockIdx.x;
    float il2 = 1.0f/(ls[c]*ls[c]);
    float vc = var[c], nc = noise[c];
    float4 xi = ((const float4*)Xtr)[i];
    float* row = Lbuf + ((size_t)c*N + i)*N;
    for (int j = threadIdx.x; j < N; j += blockDim.x){
        float4 xj = ((const float4*)Xtr)[j];
        float d2 = sqdist4(xi,xj);
        float v = vc*__expf(-0.5f*d2*il2);
        if (j==i) v += nc;
        row[j] = v;
    }
}

// Factor 128x128 diag block (lower), then invert it in LDS; write inverse
// (lower, zero upper) to Dinv. Never writes Lbuf.
__global__ __launch_bounds__(256) void k_diag(const float* __restrict__ Lbuf,
                                              float* __restrict__ Dinv, int kb){
    __shared__ float T[NB][NB];
    int c = blockIdx.x;
    const float* A = Lbuf + (size_t)c*N*N + (size_t)kb*NB*N + kb*NB;
    int tid = threadIdx.x;
    for (int idx = tid; idx < NB*NB; idx += 256){
        int r = idx >> 7, col = idx & 127;
        T[r][col] = A[(size_t)r*N + col];
    }
    __syncthreads();
    int ty = tid >> 4, tx = tid & 15;
    // Cholesky (right-looking, rank-1 on trailing square; upper is junk but never read)
    for (int j = 0; j < NB; j++){
        if (tid == 0) T[j][j] = sqrtf(T[j][j]);
        __syncthreads();
        float invd = 1.0f / T[j][j];
        for (int i = j+1+tid; i < NB; i += 256) T[i][j] *= invd;
        __syncthreads();
        for (int i = j+1+ty; i < NB; i += 16){
            float tij = T[i][j];
            for (int k = j+1+tx; k < NB; k += 16)
                T[i][k] -= tij * T[k][j];
        }
        __syncthreads();
    }
    // in-place lower-triangular inversion
    for (int i = 0; i < NB; i++){
        float inv_ii = 1.0f / T[i][i];
        float S = 0.0f;
        int j = tid;
        if (j < i){
            for (int k = j; k < i; k++) S += T[i][k] * T[k][j];
        }
        __syncthreads();
        if (j < i) T[i][j] = -inv_ii * S;
        if (tid == i) T[i][i] = inv_ii;
        __syncthreads();
    }
    float* Dv = Dinv + ((size_t)c*TB + kb)*NB*NB;
    for (int idx = tid; idx < NB*NB; idx += 256){
        int r = idx >> 7, col = idx & 127;
        Dv[idx] = (col <= r) ? T[r][col] : 0.0f;
    }
}

// panel TRSM as GEMM: L[ib,kb] = A[ib,kb] @ Dinv_kb^T   (in place)
__global__ __launch_bounds__(256) void k_panel(float* __restrict__ Lbuf,
                                               const float* __restrict__ Dinv, int kb){
    __shared__ float As[32][NB+PAD];
    __shared__ float Bs[32][NB+PAD];
    int c = blockIdx.x;
    int ib = kb + 1 + blockIdx.y;
    float* Ablk = Lbuf + (size_t)c*N*N + (size_t)ib*NB*N + kb*NB;
    const float* Dv = Dinv + ((size_t)c*TB + kb)*NB*NB;
    float acc[8][8] = {};
    gemm_core(Ablk, N, Dv, NB, NB, true, acc, As, Bs);
    store_acc(Ablk, N, acc, 1.0f);
}

// trailing update: A[i,j] -= P_i @ P_j^T  for kb < j <= i
__global__ __launch_bounds__(256) void k_syrk(float* __restrict__ Lbuf, int kb){
    __shared__ float As[32][NB+PAD];
    __shared__ float Bs[32][NB+PAD];
    int c = blockIdx.x;
    int flat = blockIdx.y;
    int di = 0; while ((di+1)*(di+2)/2 <= flat) di++;
    int dj = flat - di*(di+1)/2;
    int i = kb+1+di, j = kb+1+dj;
    float* base = Lbuf + (size_t)c*N*N;
    float* Cblk = base + (size_t)i*NB*N + j*NB;
    const float* Ablk = base + (size_t)i*NB*N + kb*NB;
    const float* Bblk = base + (size_t)j*NB*N + kb*NB;
    float acc[8][8] = {};
    gemm_core(Ablk, N, Bblk, N, NB, true, acc, As, Bs);
    int tid=threadIdx.x;
    int r0 = (tid >> 4) * 8, ca = (tid & 15) * 4, cb = 64 + ca;
    #pragma unroll
    for (int u=0;u<8;u++){
        float4 c0v = *(float4*)&Cblk[(size_t)(r0+u)*N + ca];
        float4 c1v = *(float4*)&Cblk[(size_t)(r0+u)*N + cb];
        c0v.x -= acc[u][0]; c0v.y -= acc[u][1]; c0v.z -= acc[u][2]; c0v.w -= acc[u][3];
        c1v.x -= acc[u][4]; c1v.y -= acc[u][5]; c1v.z -= acc[u][6]; c1v.w -= acc[u][7];
        *(float4*)&Cblk[(size_t)(r0+u)*N + ca] = c0v;
        *(float4*)&Cblk[(size_t)(r0+u)*N + cb] = c1v;
    }
}

// write W[i,i] = Dinv_i (including zero upper) into Lbuf diag blocks
__global__ void k_write_diag(float* __restrict__ Lbuf, const float* __restrict__ Dinv){
    int c = blockIdx.x, i = blockIdx.y;
    const float* S = Dinv + ((size_t)c*TB + i)*NB*NB;
    float* Dst = Lbuf + (size_t)c*N*N + (size_t)i*NB*N + i*NB;
    for (int idx = threadIdx.x; idx < NB*NB; idx += blockDim.x){
        int r = idx>>7, col = idx&127;
        Dst[(size_t)r*N + col] = S[idx];
    }
}

// Trow[c] = L[ib, kt] block copy (original L row-block)
__global__ void k_copy_row(float* __restrict__ Trow, const float* __restrict__ Lbuf, int ib){
    int c = blockIdx.x, kt = blockIdx.y;
    const float* src = Lbuf + (size_t)c*N*N + (size_t)ib*NB*N + kt*NB;
    float* dst = Trow + (size_t)c*NB*N + kt*NB;
    for (int idx = threadIdx.x; idx < NB*32; idx += blockDim.x){
        int r = idx>>5, col4 = (idx&31)*4;
        *(float4*)&dst[(size_t)r*N+col4] = *(const float4*)&src[(size_t)r*N+col4];
    }
}

// G = Dinv_ib @ Trow   (in place per column-tile)
__global__ __launch_bounds__(256) void k_gemmA(float* __restrict__ Trow,
                                               const float* __restrict__ Dinv, int ib){
    __shared__ float As[32][NB+PAD];
    __shared__ float Bs[32][NB+PAD];
    int c = blockIdx.x, ct = blockIdx.y;
    const float* Dv = Dinv + ((size_t)c*TB + ib)*NB*NB;
    float* Tr = Trow + (size_t)c*NB*N;
    float acc[8][8] = {};
    gemm_core(Dv, NB, Tr + ct*NB, N, NB, false, acc, As, Bs);
    store_acc(Tr + ct*NB, N, acc, 1.0f);
}

// W[ib,jt] = - sum_{kt=jt..ib-1} G[:,kt] @ W[kt,jt]
__global__ __launch_bounds__(256) void k_gemmB(float* __restrict__ Lbuf,
                                               const float* __restrict__ Trow, int ib){
    __shared__ float As[32][NB+PAD];
    __shared__ float Bs[32][NB+PAD];
    int c = blockIdx.x, jt = blockIdx.y;
    const float* G = Trow + (size_t)c*NB*N;
    float* base = Lbuf + (size_t)c*N*N;
    int klen = (ib - jt)*NB;
    int k0g = jt*NB;
    float acc[8][8] = {};
    gemm_core(G + k0g, N, base + (size_t)k0g*N + jt*NB, N, klen, false, acc, As, Bs);
    store_acc(base + (size_t)ib*NB*N + jt*NB, N, acc, -1.0f);
}

// z[c] = W y  (triangular matvec, one wave per row)
__global__ void k_zvec(const float* __restrict__ Lbuf, const float* __restrict__ y,
                       float* __restrict__ z){
    int c = blockIdx.x;
    int p = blockIdx.y * 4 + (threadIdx.x >> 6);
    int lane = threadIdx.x & 63;
    const float* row = Lbuf + (size_t)c*N*N + (size_t)p*N;
    float s = 0.0f;
    for (int i = lane; i <= p; i += 64) s += row[i]*y[i];
    for (int off = 32; off; off >>= 1) s += __shfl_down(s, off);
    if (lane == 0) z[c*N + p] = s;
}

// Fused: A = Kt @ W^T tile, reduce rowwise into mean/var accumulators.
// acc_out[0..M) = mean sum, acc_out[M..2M) = var sum.
__global__ __launch_bounds__(256) void k_bigg(const float* __restrict__ Lbuf,
                                              const float* __restrict__ d2,
                                              const float* __restrict__ zbuf,
                                              const float* __restrict__ ls,
                                              const float* __restrict__ var,
                                              float* __restrict__ acc_out){
    __shared__ float As[32][NB+PAD];
    __shared__ float Bs[32][NB+PAD];
    __shared__ float red[NB][17];
    int jt = blockIdx.x, pt = blockIdx.y, c = blockIdx.z;
    int tid = threadIdx.x, tx = tid&15, ty = tid>>4;
    int r0 = ty*8, ca = tx*4, cb = 64 + ca;
    float il2 = 1.0f/(ls[c]*ls[c]);
    float vc = var[c];
    const float* W = Lbuf + (size_t)c*N*N;
    int klen = (pt+1)*NB;   // W row p has support only for k <= p (triangular skip)
    float acc[8][8] = {};
    for (int k0 = 0; k0 < klen; k0 += 32){
        {   // A tile: Kt[jt*128+cpos][k0+kk] = vc*exp(-0.5*il2*d2[k0+kk][jt*128+cpos])
            int cpos = tid & 127, kk0 = tid >> 7;
            for (int kk = kk0; kk < 32; kk += 2){
                float dv = d2[(size_t)(k0+kk)*M + jt*NB + cpos];
                As[kk][cpos] = vc * __expf(-0.5f*il2*dv);
            }
        }
        // B tile: W[pt*128+cc][k0+k], transposed load
        load_tileT(Bs, W + (size_t)(pt*NB)*N + k0, N, tid);
        __syncthreads();
        mm32(As, Bs, r0, ca, cb, acc);
        __syncthreads();
    }
    float zv[8];
    #pragma unroll
    for (int v=0;v<4;v++) zv[v]   = zbuf[c*N + pt*NB + ca + v];
    #pragma unroll
    for (int v=0;v<4;v++) zv[4+v] = zbuf[c*N + pt*NB + cb + v];
    float pv[8], pm[8];
    #pragma unroll
    for (int u=0;u<8;u++){
        float sv = 0.0f, sm = 0.0f;
        #pragma unroll
        for (int v=0;v<8;v++){ sv += acc[u][v]*acc[u][v]; sm += acc[u][v]*zv[v]; }
        pv[u] = sv; pm[u] = sm;
    }
    #pragma unroll
    for (int u=0;u<8;u++) red[r0+u][tx] = pv[u];
    __syncthreads();
    if (tid < NB){
        float s = 0.0f;
        for (int t=0;t<16;t++) s += red[tid][t];
        atomicAdd(&acc_out[M + jt*NB + tid], s);
    }
    __syncthreads();
    #pragma unroll
    for (int u=0;u<8;u++) red[r0+u][tx] = pm[u];
    __syncthreads();
    if (tid < NB){
        float s = 0.0f;
        for (int t=0;t<16;t++) s += red[tid][t];
        atomicAdd(&acc_out[jt*NB + tid], s);
    }
}

__global__ void k_final(const float* __restrict__ acc, float* __restrict__ out){
    int i = blockIdx.x*blockDim.x + threadIdx.x;
    if (i < 2*M) out[i] = acc[i] * (1.0f/64.0f);
}

// ---------------- launch ----------------
// Chains are independent; per-chain ws = N*N (Lbuf) + TB*NB*NB (Dinv)
//   + NB*N (Trow) + N (z) floats = 5.25 MB. Batch chains to fit ws_size.

extern "C" void kernel_launch(void* const* d_in, const int* in_sizes, int n_in,
                              void* d_out, int out_size, void* d_ws, size_t ws_size,
                              hipStream_t stream) {
    const float* Xtr = (const float*)d_in[0];
    const float* ytr = (const float*)d_in[1];
    const float* Xte = (const float*)d_in[2];
    const float* ls  = (const float*)d_in[3];
    const float* var = (const float*)d_in[4];
    const float* noi = (const float*)d_in[5];
    float* out = (float*)d_out;

    float* ws = (float*)d_ws;
    const size_t shared_fl  = (size_t)N*M + 2*M;              // d2te + acc
    const size_t perchain   = (size_t)N*N + (size_t)TB*NB*NB
                            + (size_t)NB*N + (size_t)N;       // Lbuf+Dinv+Trow+z
    size_t avail = ws_size / sizeof(float);
    if (avail < shared_fl + perchain) return;   // cannot run even 1 chain
    int Gmax = (int)((avail - shared_fl) / perchain);
    if (Gmax > C) Gmax = C;
    int nbatch = (C + Gmax - 1) / Gmax;
    int G = (C + nbatch - 1) / nbatch;          // balanced batches

    float* d2te = ws;
    float* acc  = d2te + (size_t)N*M;
    float* Lbuf = acc  + 2*M;
    float* Dinv = Lbuf + (size_t)G*N*N;
    float* Trow = Dinv + (size_t)G*TB*NB*NB;
    float* zbuf = Trow + (size_t)G*NB*N;

    k_init_acc<<<dim3((2*M+255)/256), dim3(256), 0, stream>>>(acc);
    k_build_d2te<<<dim3(N), dim3(256), 0, stream>>>(Xtr, Xte, d2te);

    for (int c0 = 0; c0 < C; c0 += G){
        int g = C - c0 < G ? C - c0 : G;

        k_build_K<<<dim3(N, g), dim3(256), 0, stream>>>(Xtr, ls+c0, var+c0, noi+c0, Lbuf);

        for (int kb = 0; kb < TB; kb++){
            k_diag<<<dim3(g), dim3(256), 0, stream>>>(Lbuf, Dinv, kb);
            int rem = TB-1-kb;
            if (rem > 0){
                k_panel<<<dim3(g, rem), dim3(256), 0, stream>>>(Lbuf, Dinv, kb);
                k_syrk<<<dim3(g, rem*(rem+1)/2), dim3(256), 0, stream>>>(Lbuf, kb);
            }
        }
        k_write_diag<<<dim3(g, TB), dim3(256), 0, stream>>>(Lbuf, Dinv);
        for (int ib = 1; ib < TB; ib++){
            k_copy_row<<<dim3(g, ib), dim3(256), 0, stream>>>(Trow, Lbuf, ib);
            k_gemmA<<<dim3(g, ib), dim3(256), 0, stream>>>(Trow, Dinv, ib);
            k_gemmB<<<dim3(g, ib), dim3(256), 0, stream>>>(Lbuf, Trow, ib);
        }
        k_zvec<<<dim3(g, N/4), dim3(256), 0, stream>>>(Lbuf, ytr, zbuf);
        k_bigg<<<dim3(M/NB, TB, g), dim3(256), 0, stream>>>(Lbuf, d2te, zbuf, ls+c0, var+c0, acc);
    }
    k_final<<<dim3((2*M+255)/256), dim3(256), 0, stream>>>(acc, out);
}

// Round 4
// 13680.190 us; speedup vs baseline: 1.2918x; 1.1544x over previous
//
#include <hip/hip_runtime.h>
#include <math.h>

#define N 1024
#define M 2048
#define C 64
#define NB 128
#define TB 8   // N/NB
#define PAD 4  // f32 LDS row pad
#define TP 40  // bf16 tile pitch in shorts (20 dwords -> even bank spread)

typedef __attribute__((ext_vector_type(8))) short bf16x8;
typedef __attribute__((ext_vector_type(4))) float f32x4;

// ---------------- helpers ----------------

__device__ __forceinline__ float sqdist4(const float4 a, const float4 b){
    float dx=a.x-b.x, dy=a.y-b.y, dz=a.z-b.z, dw=a.w-b.w;
    return dx*dx+dy*dy+dz*dz+dw*dw;
}

// split 4 floats into hi(trunc-bf16) and lo(bf16 of residual), packed 2/dword
__device__ __forceinline__ void split4(float x0, float x1, float x2, float x3,
                                       uint2& hi, uint2& lo){
    unsigned b0=__float_as_uint(x0), b1=__float_as_uint(x1),
             b2=__float_as_uint(x2), b3=__float_as_uint(x3);
    unsigned h0=b0&0xFFFF0000u, h1=b1&0xFFFF0000u, h2=b2&0xFFFF0000u, h3=b3&0xFFFF0000u;
    hi.x = (h0>>16)|h1;  hi.y = (h2>>16)|h3;
    float l0=x0-__uint_as_float(h0), l1=x1-__uint_as_float(h1),
          l2=x2-__uint_as_float(h2), l3=x3-__uint_as_float(h3);
    lo.x = (__float_as_uint(l0)>>16) | (__float_as_uint(l1)&0xFFFF0000u);
    lo.y = (__float_as_uint(l2)>>16) | (__float_as_uint(l3)&0xFFFF0000u);
}

// ---- f32 vector-GEMM core (Cholesky path, unchanged from round 3) ----

__device__ __forceinline__ void load_tileT(float Ts[32][NB+PAD], const float* __restrict__ S,
                                           int lds_, int tid){
    int k4 = (tid & 7) * 4, c0 = tid >> 3;
    #pragma unroll
    for (int cc = c0; cc < NB; cc += 32){
        float4 v = *(const float4*)&S[(size_t)cc*lds_ + k4];
        Ts[k4+0][cc] = v.x; Ts[k4+1][cc] = v.y; Ts[k4+2][cc] = v.z; Ts[k4+3][cc] = v.w;
    }
}

__device__ __forceinline__ void load_tileS(float Ts[32][NB+PAD], const float* __restrict__ S,
                                           int lds_, int tid){
    int c4 = (tid & 31) * 4, kk = tid >> 5;
    #pragma unroll
    for (int k = kk; k < 32; k += 8){
        float4 v = *(const float4*)&S[(size_t)k*lds_ + c4];
        *(float4*)&Ts[k][c4] = v;
    }
}

__device__ __forceinline__ void mm32(const float As[32][NB+PAD], const float Bs[32][NB+PAD],
                                     int r0, int ca, int cb, float acc[8][8]){
    #pragma unroll 8
    for (int k = 0; k < 32; k++){
        float4 a0 = *(const float4*)&As[k][r0];
        float4 a1 = *(const float4*)&As[k][r0+4];
        float4 b0 = *(const float4*)&Bs[k][ca];
        float4 b1 = *(const float4*)&Bs[k][cb];
        float a[8] = {a0.x,a0.y,a0.z,a0.w,a1.x,a1.y,a1.z,a1.w};
        float b[8] = {b0.x,b0.y,b0.z,b0.w,b1.x,b1.y,b1.z,b1.w};
        #pragma unroll
        for (int u=0;u<8;u++)
            #pragma unroll
            for (int v=0;v<8;v++)
                acc[u][v] += a[u]*b[v];
    }
}

__device__ __forceinline__ void gemm_core(const float* __restrict__ A, int lda,
                                          const float* __restrict__ B, int ldb,
                                          int klen, bool bT, float acc[8][8],
                                          float As[32][NB+PAD], float Bs[32][NB+PAD])
{
    int tid = threadIdx.x;
    int r0 = (tid >> 4) * 8, ca = (tid & 15) * 4, cb = 64 + ca;
    for (int k0 = 0; k0 < klen; k0 += 32){
        load_tileT(As, A + k0, lda, tid);
        if (bT) load_tileT(Bs, B + k0, ldb, tid);
        else    load_tileS(Bs, B + (size_t)k0*ldb, ldb, tid);
        __syncthreads();
        mm32(As, Bs, r0, ca, cb, acc);
        __syncthreads();
    }
}

__device__ __forceinline__ void store_acc(float* __restrict__ Cp, int ldc,
                                          const float acc[8][8], float sgn){
    int tid = threadIdx.x;
    int r0 = (tid >> 4) * 8, ca = (tid & 15) * 4, cb = 64 + ca;
    #pragma unroll
    for (int u=0;u<8;u++){
        float4 v0 = make_float4(sgn*acc[u][0], sgn*acc[u][1], sgn*acc[u][2], sgn*acc[u][3]);
        float4 v1 = make_float4(sgn*acc[u][4], sgn*acc[u][5], sgn*acc[u][6], sgn*acc[u][7]);
        *(float4*)&Cp[(size_t)(r0+u)*ldc + ca] = v0;
        *(float4*)&Cp[(size_t)(r0+u)*ldc + cb] = v1;
    }
}

// ---------------- kernels ----------------

__global__ void k_init_acc(float* __restrict__ acc){
    int i = blockIdx.x*blockDim.x + threadIdx.x;
    if (i < 2*M) acc[i] = 0.0f;
}

// d2te[j][i] = ||Xte_j - Xtr_i||^2   (M x N, row per test point)
__global__ void k_build_d2te(const float* __restrict__ Xtr, const float* __restrict__ Xte,
                             float* __restrict__ d2){
    int j = blockIdx.x;
    float4 xj = ((const float4*)Xte)[j];
    for (int i = threadIdx.x; i < N; i += blockDim.x){
        float4 xi = ((const float4*)Xtr)[i];
        d2[(size_t)j*N + i] = sqdist4(xi,xj);
    }
}

// K_noisy for chain c (batch-local) into Lbuf[c]
__global__ void k_build_K(const float* __restrict__ Xtr, const float* __restrict__ ls,
                          const float* __restrict__ var, const float* __restrict__ noise,
                          float* __restrict__ Lbuf){
    int c = blockIdx.y;
    int i = blockIdx.x;
    float il2 = 1.0f/(ls[c]*ls[c]);
    float vc = var[c], nc = noise[c];
    float4 xi = ((const float4*)Xtr)[i];
    float* row = Lbuf + ((size_t)c*N + i)*N;
    for (int j = threadIdx.x; j < N; j += blockDim.x){
        float4 xj = ((const float4*)Xtr)[j];
        float d2 = sqdist4(xi,xj);
        float v = vc*__expf(-0.5f*d2*il2);
        if (j==i) v += nc;
        row[j] = v;
    }
}

// Factor 128x128 diag block, invert in LDS; write inverse (zero upper)
// to Dinv AND into Lbuf's diag block (W[i,i]) -- write_diag fused.
__global__ __launch_bounds__(256) void k_diag(float* __restrict__ Lbuf,
                                              float* __restrict__ Dinv, int kb){
    __shared__ float T[NB][NB];
    int c = blockIdx.x;
    float* A = Lbuf + (size_t)c*N*N + (size_t)kb*NB*N + kb*NB;
    int tid = threadIdx.x;
    for (int idx = tid; idx < NB*NB; idx += 256){
        int r = idx >> 7, col = idx & 127;
        T[r][col] = A[(size_t)r*N + col];
    }
    __syncthreads();
    int ty = tid >> 4, tx = tid & 15;
    for (int j = 0; j < NB; j++){
        if (tid == 0) T[j][j] = sqrtf(T[j][j]);
        __syncthreads();
        float invd = 1.0f / T[j][j];
        for (int i = j+1+tid; i < NB; i += 256) T[i][j] *= invd;
        __syncthreads();
        for (int i = j+1+ty; i < NB; i += 16){
            float tij = T[i][j];
            for (int k = j+1+tx; k < NB; k += 16)
                T[i][k] -= tij * T[k][j];
        }
        __syncthreads();
    }
    for (int i = 0; i < NB; i++){
        float inv_ii = 1.0f / T[i][i];
        float S = 0.0f;
        int j = tid;
        if (j < i){
            for (int k = j; k < i; k++) S += T[i][k] * T[k][j];
        }
        __syncthreads();
        if (j < i) T[i][j] = -inv_ii * S;
        if (tid == i) T[i][i] = inv_ii;
        __syncthreads();
    }
    float* Dv = Dinv + ((size_t)c*TB + kb)*NB*NB;
    for (int idx = tid; idx < NB*NB; idx += 256){
        int r = idx >> 7, col = idx & 127;
        float v = (col <= r) ? T[r][col] : 0.0f;
        Dv[idx] = v;
        A[(size_t)r*N + col] = v;
    }
}

// panel TRSM as GEMM: L[ib,kb] = A[ib,kb] @ Dinv_kb^T   (in place)
__global__ __launch_bounds__(256) void k_panel(float* __restrict__ Lbuf,
                                               const float* __restrict__ Dinv, int kb){
    __shared__ float As[32][NB+PAD];
    __shared__ float Bs[32][NB+PAD];
    int c = blockIdx.x;
    int ib = kb + 1 + blockIdx.y;
    float* Ablk = Lbuf + (size_t)c*N*N + (size_t)ib*NB*N + kb*NB;
    const float* Dv = Dinv + ((size_t)c*TB + kb)*NB*NB;
    float acc[8][8] = {};
    gemm_core(Ablk, N, Dv, NB, NB, true, acc, As, Bs);
    store_acc(Ablk, N, acc, 1.0f);
}

// trailing update: A[i,j] -= P_i @ P_j^T
__global__ __launch_bounds__(256) void k_syrk(float* __restrict__ Lbuf, int kb){
    __shared__ float As[32][NB+PAD];
    __shared__ float Bs[32][NB+PAD];
    int c = blockIdx.x;
    int flat = blockIdx.y;
    int di = 0; while ((di+1)*(di+2)/2 <= flat) di++;
    int dj = flat - di*(di+1)/2;
    int i = kb+1+di, j = kb+1+dj;
    float* base = Lbuf + (size_t)c*N*N;
    float* Cblk = base + (size_t)i*NB*N + j*NB;
    const float* Ablk = base + (size_t)i*NB*N + kb*NB;
    const float* Bblk = base + (size_t)j*NB*N + kb*NB;
    float acc[8][8] = {};
    gemm_core(Ablk, N, Bblk, N, NB, true, acc, As, Bs);
    int tid=threadIdx.x;
    int r0 = (tid >> 4) * 8, ca = (tid & 15) * 4, cb = 64 + ca;
    #pragma unroll
    for (int u=0;u<8;u++){
        float4 c0v = *(float4*)&Cblk[(size_t)(r0+u)*N + ca];
        float4 c1v = *(float4*)&Cblk[(size_t)(r0+u)*N + cb];
        c0v.x -= acc[u][0]; c0v.y -= acc[u][1]; c0v.z -= acc[u][2]; c0v.w -= acc[u][3];
        c1v.x -= acc[u][4]; c1v.y -= acc[u][5]; c1v.z -= acc[u][6]; c1v.w -= acc[u][7];
        *(float4*)&Cblk[(size_t)(r0+u)*N + ca] = c0v;
        *(float4*)&Cblk[(size_t)(r0+u)*N + cb] = c1v;
    }
}

// G = Dinv_ib @ L[ib, :]  (reads Lbuf directly, writes Trow; copy_row fused away)
__global__ __launch_bounds__(256) void k_gemmA(float* __restrict__ Trow,
                                               const float* __restrict__ Lbuf,
                                               const float* __restrict__ Dinv, int ib){
    __shared__ float As[32][NB+PAD];
    __shared__ float Bs[32][NB+PAD];
    int c = blockIdx.x, ct = blockIdx.y;
    const float* Dv = Dinv + ((size_t)c*TB + ib)*NB*NB;
    const float* Bsrc = Lbuf + (size_t)c*N*N + (size_t)(ib*NB)*N + ct*NB;
    float acc[8][8] = {};
    gemm_core(Dv, NB, Bsrc, N, NB, false, acc, As, Bs);
    store_acc(Trow + (size_t)c*NB*N + ct*NB, N, acc, 1.0f);
}

// W[ib,jt] = - sum_{kt=jt..ib-1} G[:,kt] @ W[kt,jt]
__global__ __launch_bounds__(256) void k_gemmB(float* __restrict__ Lbuf,
                                               const float* __restrict__ Trow, int ib){
    __shared__ float As[32][NB+PAD];
    __shared__ float Bs[32][NB+PAD];
    int c = blockIdx.x, jt = blockIdx.y;
    const float* G = Trow + (size_t)c*NB*N;
    float* base = Lbuf + (size_t)c*N*N;
    int klen = (ib - jt)*NB;
    int k0g = jt*NB;
    float acc[8][8] = {};
    gemm_core(G + k0g, N, base + (size_t)k0g*N + jt*NB, N, klen, false, acc, As, Bs);
    store_acc(base + (size_t)ib*NB*N + jt*NB, N, acc, -1.0f);
}

// z[c] = W y  (triangular matvec, one wave per row)
__global__ void k_zvec(const float* __restrict__ Lbuf, const float* __restrict__ y,
                       float* __restrict__ z){
    int c = blockIdx.x;
    int p = blockIdx.y * 4 + (threadIdx.x >> 6);
    int lane = threadIdx.x & 63;
    const float* row = Lbuf + (size_t)c*N*N + (size_t)p*N;
    float s = 0.0f;
    for (int i = lane; i <= p; i += 64) s += row[i]*y[i];
    for (int off = 32; off; off >>= 1) s += __shfl_down(s, off);
    if (lane == 0) z[c*N + p] = s;
}

// Fused A = Kte @ W^T via split-bf16 MFMA; rowwise mean/var reduction.
// acc_out[0..M) = mean sums, acc_out[M..2M) = var sums.
__global__ __launch_bounds__(256) void k_bigg(const float* __restrict__ Lbuf,
                                              const float* __restrict__ d2,   // [M][N]
                                              const float* __restrict__ zbuf,
                                              const float* __restrict__ ls,
                                              const float* __restrict__ var,
                                              float* __restrict__ acc_out){
    __shared__ unsigned short Ah[NB][TP], Al[NB][TP], Bh[NB][TP], Bl[NB][TP];
    int jt = blockIdx.x, pt = blockIdx.y, c = blockIdx.z;
    int tid = threadIdx.x;
    int lane = tid & 63, w = tid >> 6;
    int wrow = w >> 1, wcol = w & 1;
    float il2 = 1.0f/(ls[c]*ls[c]);
    float vc = var[c];
    float ec = -0.5f*il2;
    const float* Arow = d2 + (size_t)(jt*NB)*N;            // [row][k]
    const float* Brow = Lbuf + (size_t)c*N*N + (size_t)(pt*NB)*N;  // W rows [p][k]
    int klen = (pt+1)*NB;   // triangular skip
    f32x4 acc[4][4];
    #pragma unroll
    for (int i=0;i<4;i++)
        #pragma unroll
        for (int j=0;j<4;j++) acc[i][j] = (f32x4)0.0f;

    int q = tid & 7, rs = tid >> 3;          // staging: q=float4 slot, rs=row base
    int fr = lane & 15, kg = lane >> 4;      // fragment row/col & k-group
    int ar = wrow*64 + fr, br = wcol*64 + fr;
    int kc = kg * 8;

    for (int k0 = 0; k0 < klen; k0 += 32){
        __syncthreads();
        #pragma unroll
        for (int p = 0; p < 4; p++){
            int r = rs + 32*p;
            float4 dv = *(const float4*)&Arow[(size_t)r*N + k0 + q*4];
            float x0 = vc*__expf(ec*dv.x), x1 = vc*__expf(ec*dv.y);
            float x2 = vc*__expf(ec*dv.z), x3 = vc*__expf(ec*dv.w);
            uint2 hi, lo; split4(x0,x1,x2,x3, hi, lo);
            *(uint2*)&Ah[r][q*4] = hi;
            *(uint2*)&Al[r][q*4] = lo;
        }
        #pragma unroll
        for (int p = 0; p < 4; p++){
            int r = rs + 32*p;
            float4 wv = *(const float4*)&Brow[(size_t)r*N + k0 + q*4];
            uint2 hi, lo; split4(wv.x,wv.y,wv.z,wv.w, hi, lo);
            *(uint2*)&Bh[r][q*4] = hi;
            *(uint2*)&Bl[r][q*4] = lo;
        }
        __syncthreads();
        bf16x8 ah[4], al[4];
        #pragma unroll
        for (int rt=0;rt<4;rt++){
            ah[rt] = *(const bf16x8*)&Ah[ar + rt*16][kc];
            al[rt] = *(const bf16x8*)&Al[ar + rt*16][kc];
        }
        #pragma unroll
        for (int ct=0;ct<4;ct++){
            bf16x8 bh = *(const bf16x8*)&Bh[br + ct*16][kc];
            bf16x8 bl = *(const bf16x8*)&Bl[br + ct*16][kc];
            #pragma unroll
            for (int rt=0;rt<4;rt++){
                f32x4 a = acc[rt][ct];
                a = __builtin_amdgcn_mfma_f32_16x16x32_bf16(ah[rt], bh, a, 0,0,0);
                a = __builtin_amdgcn_mfma_f32_16x16x32_bf16(ah[rt], bl, a, 0,0,0);
                a = __builtin_amdgcn_mfma_f32_16x16x32_bf16(al[rt], bh, a, 0,0,0);
                acc[rt][ct] = a;
            }
        }
    }
    // epilogue: D[row=4*kg+r][col=fr] per sub-tile; reduce over 16-lane groups
    float zv[4];
    #pragma unroll
    for (int ct=0;ct<4;ct++) zv[ct] = zbuf[c*N + pt*NB + wcol*64 + ct*16 + fr];
    #pragma unroll
    for (int rt=0;rt<4;rt++){
        #pragma unroll
        for (int r=0;r<4;r++){
            float m = 0.0f, v = 0.0f;
            #pragma unroll
            for (int ct=0;ct<4;ct++){
                float x = acc[rt][ct][r];
                v += x*x; m += x*zv[ct];
            }
            m += __shfl_xor(m, 1);  v += __shfl_xor(v, 1);
            m += __shfl_xor(m, 2);  v += __shfl_xor(v, 2);
            m += __shfl_xor(m, 4);  v += __shfl_xor(v, 4);
            m += __shfl_xor(m, 8);  v += __shfl_xor(v, 8);
            if (fr == 0){
                int j = jt*NB + wrow*64 + rt*16 + kg*4 + r;
                atomicAdd(&acc_out[j], m);
                atomicAdd(&acc_out[M + j], v);
            }
        }
    }
}

__global__ void k_final(const float* __restrict__ acc, float* __restrict__ out){
    int i = blockIdx.x*blockDim.x + threadIdx.x;
    if (i < 2*M) out[i] = acc[i] * (1.0f/64.0f);
}

// ---------------- launch ----------------

extern "C" void kernel_launch(void* const* d_in, const int* in_sizes, int n_in,
                              void* d_out, int out_size, void* d_ws, size_t ws_size,
                              hipStream_t stream) {
    const float* Xtr = (const float*)d_in[0];
    const float* ytr = (const float*)d_in[1];
    const float* Xte = (const float*)d_in[2];
    const float* ls  = (const float*)d_in[3];
    const float* var = (const float*)d_in[4];
    const float* noi = (const float*)d_in[5];
    float* out = (float*)d_out;

    float* ws = (float*)d_ws;
    const size_t shared_fl  = (size_t)N*M + 2*M;              // d2te + acc
    const size_t perchain   = (size_t)N*N + (size_t)TB*NB*NB
                            + (size_t)NB*N + (size_t)N;       // Lbuf+Dinv+Trow+z
    size_t avail = ws_size / sizeof(float);
    if (avail < shared_fl + perchain) return;
    int Gmax = (int)((avail - shared_fl) / perchain);
    if (Gmax > C) Gmax = C;
    int nbatch = (C + Gmax - 1) / Gmax;
    int G = (C + nbatch - 1) / nbatch;          // balanced batches

    float* d2te = ws;
    float* acc  = d2te + (size_t)N*M;
    float* Lbuf = acc  + 2*M;
    float* Dinv = Lbuf + (size_t)G*N*N;
    float* Trow = Dinv + (size_t)G*TB*NB*NB;
    float* zbuf = Trow + (size_t)G*NB*N;

    k_init_acc<<<dim3((2*M+255)/256), dim3(256), 0, stream>>>(acc);
    k_build_d2te<<<dim3(M), dim3(256), 0, stream>>>(Xtr, Xte, d2te);

    for (int c0 = 0; c0 < C; c0 += G){
        int g = C - c0 < G ? C - c0 : G;

        k_build_K<<<dim3(N, g), dim3(256), 0, stream>>>(Xtr, ls+c0, var+c0, noi+c0, Lbuf);

        for (int kb = 0; kb < TB; kb++){
            k_diag<<<dim3(g), dim3(256), 0, stream>>>(Lbuf, Dinv, kb);
            int rem = TB-1-kb;
            if (rem > 0){
                k_panel<<<dim3(g, rem), dim3(256), 0, stream>>>(Lbuf, Dinv, kb);
                k_syrk<<<dim3(g, rem*(rem+1)/2), dim3(256), 0, stream>>>(Lbuf, kb);
            }
        }
        for (int ib = 1; ib < TB; ib++){
            k_gemmA<<<dim3(g, ib), dim3(256), 0, stream>>>(Trow, Lbuf, Dinv, ib);
            k_gemmB<<<dim3(g, ib), dim3(256), 0, stream>>>(Lbuf, Trow, ib);
        }
        k_zvec<<<dim3(g, N/4), dim3(256), 0, stream>>>(Lbuf, ytr, zbuf);
        k_bigg<<<dim3(M/NB, TB, g), dim3(256), 0, stream>>>(Lbuf, d2te, zbuf, ls+c0, var+c0, acc);
    }
    k_final<<<dim3((2*M+255)/256), dim3(256), 0, stream>>>(acc, out);
}

// Round 5
// 7995.862 us; speedup vs baseline: 2.2101x; 1.7109x over previous
//
#include <hip/hip_runtime.h>
#include <math.h>

#define N 1024
#define M 2048
#define C 64
#define NB 128
#define TB 8    // N/NB
#define PAD 4   // f32 LDS row pad
#define TP 40   // bf16 tile pitch in shorts (20 dwords -> even bank spread)
#define NBLK 36                   // TB*(TB+1)/2 lower-tri blocks
#define PL ((size_t)NBLK*NB*NB)   // packed L floats per chain

typedef __attribute__((ext_vector_type(8))) short bf16x8;
typedef __attribute__((ext_vector_type(4))) float f32x4;

__device__ __forceinline__ size_t pblk(int ib, int jt){
    return ((size_t)((ib*(ib+1))/2 + jt))*((size_t)NB*NB);
}

// ---------------- helpers ----------------

__device__ __forceinline__ float sqdist4(const float4 a, const float4 b){
    float dx=a.x-b.x, dy=a.y-b.y, dz=a.z-b.z, dw=a.w-b.w;
    return dx*dx+dy*dy+dz*dz+dw*dw;
}

__device__ __forceinline__ void split4(float x0, float x1, float x2, float x3,
                                       uint2& hi, uint2& lo){
    unsigned b0=__float_as_uint(x0), b1=__float_as_uint(x1),
             b2=__float_as_uint(x2), b3=__float_as_uint(x3);
    unsigned h0=b0&0xFFFF0000u, h1=b1&0xFFFF0000u, h2=b2&0xFFFF0000u, h3=b3&0xFFFF0000u;
    hi.x = (h0>>16)|h1;  hi.y = (h2>>16)|h3;
    float l0=x0-__uint_as_float(h0), l1=x1-__uint_as_float(h1),
          l2=x2-__uint_as_float(h2), l3=x3-__uint_as_float(h3);
    lo.x = (__float_as_uint(l0)>>16) | (__float_as_uint(l1)&0xFFFF0000u);
    lo.y = (__float_as_uint(l2)>>16) | (__float_as_uint(l3)&0xFFFF0000u);
}

// ---- f32 vector-GEMM core (conflict-free since round 3) ----

__device__ __forceinline__ void load_tileT(float Ts[32][NB+PAD], const float* __restrict__ S,
                                           int lds_, int tid){
    int k4 = (tid & 7) * 4, c0 = tid >> 3;
    #pragma unroll
    for (int cc = c0; cc < NB; cc += 32){
        float4 v = *(const float4*)&S[(size_t)cc*lds_ + k4];
        Ts[k4+0][cc] = v.x; Ts[k4+1][cc] = v.y; Ts[k4+2][cc] = v.z; Ts[k4+3][cc] = v.w;
    }
}

__device__ __forceinline__ void load_tileS(float Ts[32][NB+PAD], const float* __restrict__ S,
                                           int lds_, int tid){
    int c4 = (tid & 31) * 4, kk = tid >> 5;
    #pragma unroll
    for (int k = kk; k < 32; k += 8){
        float4 v = *(const float4*)&S[(size_t)k*lds_ + c4];
        *(float4*)&Ts[k][c4] = v;
    }
}

__device__ __forceinline__ void mm32(const float As[32][NB+PAD], const float Bs[32][NB+PAD],
                                     int r0, int ca, int cb, float acc[8][8]){
    #pragma unroll 8
    for (int k = 0; k < 32; k++){
        float4 a0 = *(const float4*)&As[k][r0];
        float4 a1 = *(const float4*)&As[k][r0+4];
        float4 b0 = *(const float4*)&Bs[k][ca];
        float4 b1 = *(const float4*)&Bs[k][cb];
        float a[8] = {a0.x,a0.y,a0.z,a0.w,a1.x,a1.y,a1.z,a1.w};
        float b[8] = {b0.x,b0.y,b0.z,b0.w,b1.x,b1.y,b1.z,b1.w};
        #pragma unroll
        for (int u=0;u<8;u++)
            #pragma unroll
            for (int v=0;v<8;v++)
                acc[u][v] += a[u]*b[v];
    }
}

__device__ __forceinline__ void gemm_core(const float* __restrict__ A, int lda,
                                          const float* __restrict__ B, int ldb,
                                          int klen, bool bT, float acc[8][8],
                                          float As[32][NB+PAD], float Bs[32][NB+PAD])
{
    int tid = threadIdx.x;
    int r0 = (tid >> 4) * 8, ca = (tid & 15) * 4, cb = 64 + ca;
    for (int k0 = 0; k0 < klen; k0 += 32){
        load_tileT(As, A + k0, lda, tid);
        if (bT) load_tileT(Bs, B + k0, ldb, tid);
        else    load_tileS(Bs, B + (size_t)k0*ldb, ldb, tid);
        __syncthreads();
        mm32(As, Bs, r0, ca, cb, acc);
        __syncthreads();
    }
}

__device__ __forceinline__ void store_acc(float* __restrict__ Cp, int ldc,
                                          const float acc[8][8], float sgn){
    int tid = threadIdx.x;
    int r0 = (tid >> 4) * 8, ca = (tid & 15) * 4, cb = 64 + ca;
    #pragma unroll
    for (int u=0;u<8;u++){
        float4 v0 = make_float4(sgn*acc[u][0], sgn*acc[u][1], sgn*acc[u][2], sgn*acc[u][3]);
        float4 v1 = make_float4(sgn*acc[u][4], sgn*acc[u][5], sgn*acc[u][6], sgn*acc[u][7]);
        *(float4*)&Cp[(size_t)(r0+u)*ldc + ca] = v0;
        *(float4*)&Cp[(size_t)(r0+u)*ldc + cb] = v1;
    }
}

// ---------------- kernels ----------------

__global__ void k_init_acc(float* __restrict__ acc){
    int i = blockIdx.x*blockDim.x + threadIdx.x;
    if (i < 2*M) acc[i] = 0.0f;
}

// d2te[j][i] = ||Xte_j - Xtr_i||^2   (M x N)
__global__ void k_build_d2te(const float* __restrict__ Xtr, const float* __restrict__ Xte,
                             float* __restrict__ d2){
    int j = blockIdx.x;
    float4 xj = ((const float4*)Xte)[j];
    for (int i = threadIdx.x; i < N; i += blockDim.x){
        float4 xi = ((const float4*)Xtr)[i];
        d2[(size_t)j*N + i] = sqdist4(xi,xj);
    }
}

// Build packed lower-tri blocks of K_noisy. grid (NBLK, g)
__global__ __launch_bounds__(256) void k_build_K(const float* __restrict__ Xtr,
                          const float* __restrict__ ls,
                          const float* __restrict__ var, const float* __restrict__ noise,
                          float* __restrict__ Lbuf){
    __shared__ float4 xr[NB], xc[NB];
    int c = blockIdx.y, flat = blockIdx.x;
    int ib = 0; while ((ib+1)*(ib+2)/2 <= flat) ib++;
    int jt = flat - ib*(ib+1)/2;
    int tid = threadIdx.x;
    if (tid < NB) xr[tid] = ((const float4*)Xtr)[ib*NB + tid];
    else          xc[tid-NB] = ((const float4*)Xtr)[jt*NB + (tid-NB)];
    __syncthreads();
    float il2 = 1.0f/(ls[c]*ls[c]);
    float vc = var[c], nc = noise[c];
    float* blk = Lbuf + c*PL + pblk(ib,jt);
    for (int idx = tid; idx < NB*NB; idx += 256){
        int r = idx >> 7, col = idx & 127;
        float d2v = sqdist4(xr[r], xc[col]);
        float v = vc*__expf(-0.5f*d2v*il2);
        if (ib==jt && r==col) v += nc;
        blk[idx] = v;
    }
}

// Factor 128x128 diag block, invert in LDS; write inverse (zero upper)
// to Dinv AND back into the packed diag block.  Rotation swizzle kills the
// stride-128 column bank conflicts (bank = (r+c)%32).
#define TT(r,c) T[r][((c)+(r)) & 127]
__global__ __launch_bounds__(256) void k_diag(float* __restrict__ Lbuf,
                                              float* __restrict__ Dinv, int kb){
    __shared__ float T[NB][NB];
    int c = blockIdx.x;
    float* A = Lbuf + c*PL + pblk(kb,kb);
    int tid = threadIdx.x;
    for (int idx = tid; idx < NB*NB; idx += 256){
        int r = idx >> 7, col = idx & 127;
        TT(r,col) = A[idx];
    }
    __syncthreads();
    int ty = tid >> 4, tx = tid & 15;
    for (int j = 0; j < NB; j++){
        if (tid == 0) TT(j,j) = sqrtf(TT(j,j));
        __syncthreads();
        float invd = 1.0f / TT(j,j);
        for (int i = j+1+tid; i < NB; i += 256) TT(i,j) *= invd;
        __syncthreads();
        for (int i = j+1+ty; i < NB; i += 16){
            float tij = TT(i,j);
            for (int k = j+1+tx; k < NB; k += 16)
                TT(i,k) -= tij * TT(k,j);
        }
        __syncthreads();
    }
    for (int i = 0; i < NB; i++){
        float inv_ii = 1.0f / TT(i,i);
        float S = 0.0f;
        int j = tid;
        if (j < i){
            for (int k = j; k < i; k++) S += TT(i,k) * TT(k,j);
        }
        __syncthreads();
        if (j < i) TT(i,j) = -inv_ii * S;
        if (tid == i) TT(i,i) = inv_ii;
        __syncthreads();
    }
    float* Dv = Dinv + ((size_t)c*TB + kb)*NB*NB;
    for (int idx = tid; idx < NB*NB; idx += 256){
        int r = idx >> 7, col = idx & 127;
        float v = (col <= r) ? TT(r,col) : 0.0f;
        Dv[idx] = v;
        A[idx] = v;
    }
}

// panel TRSM as GEMM: L[ib,kb] = L[ib,kb] @ Dinv_kb^T  (in place, packed)
__global__ __launch_bounds__(256) void k_panel(float* __restrict__ Lbuf,
                                               const float* __restrict__ Dinv, int kb){
    __shared__ float As[32][NB+PAD];
    __shared__ float Bs[32][NB+PAD];
    int c = blockIdx.x;
    int ib = kb + 1 + blockIdx.y;
    float* Ablk = Lbuf + c*PL + pblk(ib,kb);
    const float* Dv = Dinv + ((size_t)c*TB + kb)*NB*NB;
    float acc[8][8] = {};
    gemm_core(Ablk, NB, Dv, NB, NB, true, acc, As, Bs);
    store_acc(Ablk, NB, acc, 1.0f);
}

// trailing update: K[i,j] -= P_i @ P_j^T   (packed)
__global__ __launch_bounds__(256) void k_syrk(float* __restrict__ Lbuf, int kb){
    __shared__ float As[32][NB+PAD];
    __shared__ float Bs[32][NB+PAD];
    int c = blockIdx.x;
    int flat = blockIdx.y;
    int di = 0; while ((di+1)*(di+2)/2 <= flat) di++;
    int dj = flat - di*(di+1)/2;
    int i = kb+1+di, j = kb+1+dj;
    float* base = Lbuf + c*PL;
    float* Cblk = base + pblk(i,j);
    const float* Ablk = base + pblk(i,kb);
    const float* Bblk = base + pblk(j,kb);
    float acc[8][8] = {};
    gemm_core(Ablk, NB, Bblk, NB, NB, true, acc, As, Bs);
    int tid=threadIdx.x;
    int r0 = (tid >> 4) * 8, ca = (tid & 15) * 4, cb = 64 + ca;
    #pragma unroll
    for (int u=0;u<8;u++){
        float4 c0v = *(float4*)&Cblk[(size_t)(r0+u)*NB + ca];
        float4 c1v = *(float4*)&Cblk[(size_t)(r0+u)*NB + cb];
        c0v.x -= acc[u][0]; c0v.y -= acc[u][1]; c0v.z -= acc[u][2]; c0v.w -= acc[u][3];
        c1v.x -= acc[u][4]; c1v.y -= acc[u][5]; c1v.z -= acc[u][6]; c1v.w -= acc[u][7];
        *(float4*)&Cblk[(size_t)(r0+u)*NB + ca] = c0v;
        *(float4*)&Cblk[(size_t)(r0+u)*NB + cb] = c1v;
    }
}

// G(ct) = Dinv_ib @ L[ib,ct]   (reads packed L, writes Trow [NB][N])
__global__ __launch_bounds__(256) void k_gemmA(float* __restrict__ Trow,
                                               const float* __restrict__ Lbuf,
                                               const float* __restrict__ Dinv, int ib){
    __shared__ float As[32][NB+PAD];
    __shared__ float Bs[32][NB+PAD];
    int c = blockIdx.x, ct = blockIdx.y;
    const float* Dv = Dinv + ((size_t)c*TB + ib)*NB*NB;
    const float* Bsrc = Lbuf + c*PL + pblk(ib,ct);
    float acc[8][8] = {};
    gemm_core(Dv, NB, Bsrc, NB, NB, false, acc, As, Bs);
    store_acc(Trow + (size_t)c*NB*N + ct*NB, N, acc, 1.0f);
}

// W[ib,jt] = - sum_{kt=jt..ib-1} G[:,kt] @ W[kt,jt]   (packed)
__global__ __launch_bounds__(256) void k_gemmB(float* __restrict__ Lbuf,
                                               const float* __restrict__ Trow, int ib){
    __shared__ float As[32][NB+PAD];
    __shared__ float Bs[32][NB+PAD];
    int c = blockIdx.x, jt = blockIdx.y;
    const float* G = Trow + (size_t)c*NB*N;
    float* base = Lbuf + c*PL;
    float acc[8][8] = {};
    for (int kt = jt; kt < ib; kt++)
        gemm_core(G + kt*NB, N, base + pblk(kt,jt), NB, NB, false, acc, As, Bs);
    store_acc(base + pblk(ib,jt), NB, acc, -1.0f);
}

// z[c] = W y  (triangular matvec over packed blocks)
__global__ void k_zvec(const float* __restrict__ Lbuf, const float* __restrict__ y,
                       float* __restrict__ z){
    int c = blockIdx.x;
    int p = blockIdx.y * 4 + (threadIdx.x >> 6);
    int lane = threadIdx.x & 63;
    int pb = p >> 7, pl = p & 127;
    const float* base = Lbuf + c*PL;
    float s = 0.0f;
    for (int kt = 0; kt <= pb; kt++){
        const float* row = base + pblk(pb,kt) + (size_t)pl*NB;
        int lim = (kt==pb) ? pl : NB-1;
        for (int i = lane; i <= lim; i += 64) s += row[i]*y[kt*NB + i];
    }
    for (int off = 32; off; off >>= 1) s += __shfl_down(s, off);
    if (lane == 0) z[c*N + p] = s;
}

// Fused A = Kte @ W^T via split-bf16 MFMA; rowwise mean/var reduction.
__global__ __launch_bounds__(256) void k_bigg(const float* __restrict__ Lbuf,
                                              const float* __restrict__ d2,   // [M][N]
                                              const float* __restrict__ zbuf,
                                              const float* __restrict__ ls,
                                              const float* __restrict__ var,
                                              float* __restrict__ acc_out){
    __shared__ unsigned short Ah[NB][TP], Al[NB][TP], Bh[NB][TP], Bl[NB][TP];
    int jt = blockIdx.x, pt = blockIdx.y, c = blockIdx.z;
    int tid = threadIdx.x;
    int lane = tid & 63, w = tid >> 6;
    int wrow = w >> 1, wcol = w & 1;
    float il2 = 1.0f/(ls[c]*ls[c]);
    float vc = var[c];
    float ec = -0.5f*il2;
    const float* Arow = d2 + (size_t)(jt*NB)*N;
    const float* Wbase = Lbuf + c*PL;
    int klen = (pt+1)*NB;
    f32x4 acc[4][4];
    #pragma unroll
    for (int i=0;i<4;i++)
        #pragma unroll
        for (int j=0;j<4;j++) acc[i][j] = (f32x4)0.0f;

    int q = tid & 7, rs = tid >> 3;
    int fr = lane & 15, kg = lane >> 4;
    int ar = wrow*64 + fr, br = wcol*64 + fr;
    int kc = kg * 8;

    for (int k0 = 0; k0 < klen; k0 += 32){
        const float* Bp = Wbase + pblk(pt, k0 >> 7);
        int kloc = k0 & 127;
        __syncthreads();
        #pragma unroll
        for (int p = 0; p < 4; p++){
            int r = rs + 32*p;
            float4 dv = *(const float4*)&Arow[(size_t)r*N + k0 + q*4];
            float x0 = vc*__expf(ec*dv.x), x1 = vc*__expf(ec*dv.y);
            float x2 = vc*__expf(ec*dv.z), x3 = vc*__expf(ec*dv.w);
            uint2 hi, lo; split4(x0,x1,x2,x3, hi, lo);
            *(uint2*)&Ah[r][q*4] = hi;
            *(uint2*)&Al[r][q*4] = lo;
        }
        #pragma unroll
        for (int p = 0; p < 4; p++){
            int r = rs + 32*p;
            float4 wv = *(const float4*)&Bp[(size_t)r*NB + kloc + q*4];
            uint2 hi, lo; split4(wv.x,wv.y,wv.z,wv.w, hi, lo);
            *(uint2*)&Bh[r][q*4] = hi;
            *(uint2*)&Bl[r][q*4] = lo;
        }
        __syncthreads();
        bf16x8 ah[4], al[4];
        #pragma unroll
        for (int rt=0;rt<4;rt++){
            ah[rt] = *(const bf16x8*)&Ah[ar + rt*16][kc];
            al[rt] = *(const bf16x8*)&Al[ar + rt*16][kc];
        }
        #pragma unroll
        for (int ct=0;ct<4;ct++){
            bf16x8 bh = *(const bf16x8*)&Bh[br + ct*16][kc];
            bf16x8 bl = *(const bf16x8*)&Bl[br + ct*16][kc];
            #pragma unroll
            for (int rt=0;rt<4;rt++){
                f32x4 a = acc[rt][ct];
                a = __builtin_amdgcn_mfma_f32_16x16x32_bf16(ah[rt], bh, a, 0,0,0);
                a = __builtin_amdgcn_mfma_f32_16x16x32_bf16(ah[rt], bl, a, 0,0,0);
                a = __builtin_amdgcn_mfma_f32_16x16x32_bf16(al[rt], bh, a, 0,0,0);
                acc[rt][ct] = a;
            }
        }
    }
    float zv[4];
    #pragma unroll
    for (int ct=0;ct<4;ct++) zv[ct] = zbuf[c*N + pt*NB + wcol*64 + ct*16 + fr];
    #pragma unroll
    for (int rt=0;rt<4;rt++){
        #pragma unroll
        for (int r=0;r<4;r++){
            float m = 0.0f, v = 0.0f;
            #pragma unroll
            for (int ct=0;ct<4;ct++){
                float x = acc[rt][ct][r];
                v += x*x; m += x*zv[ct];
            }
            m += __shfl_xor(m, 1);  v += __shfl_xor(v, 1);
            m += __shfl_xor(m, 2);  v += __shfl_xor(v, 2);
            m += __shfl_xor(m, 4);  v += __shfl_xor(v, 4);
            m += __shfl_xor(m, 8);  v += __shfl_xor(v, 8);
            if (fr == 0){
                int j = jt*NB + wrow*64 + rt*16 + kg*4 + r;
                atomicAdd(&acc_out[j], m);
                atomicAdd(&acc_out[M + j], v);
            }
        }
    }
}

__global__ void k_final(const float* __restrict__ acc, float* __restrict__ out){
    int i = blockIdx.x*blockDim.x + threadIdx.x;
    if (i < 2*M) out[i] = acc[i] * (1.0f/64.0f);
}

// ---------------- launch ----------------
// per-chain ws = packed-L (36 blocks) + Dinv + Trow + z = 3.41 MB

extern "C" void kernel_launch(void* const* d_in, const int* in_sizes, int n_in,
                              void* d_out, int out_size, void* d_ws, size_t ws_size,
                              hipStream_t stream) {
    const float* Xtr = (const float*)d_in[0];
    const float* ytr = (const float*)d_in[1];
    const float* Xte = (const float*)d_in[2];
    const float* ls  = (const float*)d_in[3];
    const float* var = (const float*)d_in[4];
    const float* noi = (const float*)d_in[5];
    float* out = (float*)d_out;

    float* ws = (float*)d_ws;
    const size_t shared_fl  = (size_t)N*M + 2*M;              // d2te + acc
    const size_t perchain   = PL + (size_t)TB*NB*NB
                            + (size_t)NB*N + (size_t)N;       // L + Dinv + Trow + z
    size_t avail = ws_size / sizeof(float);
    if (avail < shared_fl + perchain) return;
    int Gmax = (int)((avail - shared_fl) / perchain);
    if (Gmax > C) Gmax = C;
    int nbatch = (C + Gmax - 1) / Gmax;
    int G = (C + nbatch - 1) / nbatch;          // balanced batches

    float* d2te = ws;
    float* acc  = d2te + (size_t)N*M;
    float* Lbuf = acc  + 2*M;
    float* Dinv = Lbuf + (size_t)G*PL;
    float* Trow = Dinv + (size_t)G*TB*NB*NB;
    float* zbuf = Trow + (size_t)G*NB*N;

    k_init_acc<<<dim3((2*M+255)/256), dim3(256), 0, stream>>>(acc);
    k_build_d2te<<<dim3(M), dim3(256), 0, stream>>>(Xtr, Xte, d2te);

    for (int c0 = 0; c0 < C; c0 += G){
        int g = C - c0 < G ? C - c0 : G;

        k_build_K<<<dim3(NBLK, g), dim3(256), 0, stream>>>(Xtr, ls+c0, var+c0, noi+c0, Lbuf);

        for (int kb = 0; kb < TB; kb++){
            k_diag<<<dim3(g), dim3(256), 0, stream>>>(Lbuf, Dinv, kb);
            int rem = TB-1-kb;
            if (rem > 0){
                k_panel<<<dim3(g, rem), dim3(256), 0, stream>>>(Lbuf, Dinv, kb);
                k_syrk<<<dim3(g, rem*(rem+1)/2), dim3(256), 0, stream>>>(Lbuf, kb);
            }
        }
        for (int ib = 1; ib < TB; ib++){
            k_gemmA<<<dim3(g, ib), dim3(256), 0, stream>>>(Trow, Lbuf, Dinv, ib);
            k_gemmB<<<dim3(g, ib), dim3(256), 0, stream>>>(Lbuf, Trow, ib);
        }
        k_zvec<<<dim3(g, N/4), dim3(256), 0, stream>>>(Lbuf, ytr, zbuf);
        k_bigg<<<dim3(M/NB, TB, g), dim3(256), 0, stream>>>(Lbuf, d2te, zbuf, ls+c0, var+c0, acc);
    }
    k_final<<<dim3((2*M+255)/256), dim3(256), 0, stream>>>(acc, out);
}

// Round 6
// 6212.610 us; speedup vs baseline: 2.8445x; 1.2870x over previous
//
#include <hip/hip_runtime.h>
#include <math.h>

#define N 1024
#define M 2048
#define C 64
#define NB 128
#define TB 8    // N/NB
#define PAD 4   // f32 LDS row pad
#define TP 40   // bf16 tile pitch in shorts
#define NBLK 36                   // TB*(TB+1)/2 lower-tri blocks
#define PL ((size_t)NBLK*NB*NB)   // packed L floats per chain

typedef __attribute__((ext_vector_type(8))) short bf16x8;
typedef __attribute__((ext_vector_type(4))) float f32x4;

__device__ __forceinline__ size_t pblk(int ib, int jt){
    return ((size_t)((ib*(ib+1))/2 + jt))*((size_t)NB*NB);
}

// rotate-swizzle: logical (r,c) -> physical column (c+r)&127; bank=(r+c)%32
#define TT(r,c) T[(r)][(((c)+(r)) & 127)]

// ---------------- helpers ----------------

__device__ __forceinline__ float sqdist4(const float4 a, const float4 b){
    float dx=a.x-b.x, dy=a.y-b.y, dz=a.z-b.z, dw=a.w-b.w;
    return dx*dx+dy*dy+dz*dz+dw*dw;
}

__device__ __forceinline__ void split4(float x0, float x1, float x2, float x3,
                                       uint2& hi, uint2& lo){
    unsigned b0=__float_as_uint(x0), b1=__float_as_uint(x1),
             b2=__float_as_uint(x2), b3=__float_as_uint(x3);
    unsigned h0=b0&0xFFFF0000u, h1=b1&0xFFFF0000u, h2=b2&0xFFFF0000u, h3=b3&0xFFFF0000u;
    hi.x = (h0>>16)|h1;  hi.y = (h2>>16)|h3;
    float l0=x0-__uint_as_float(h0), l1=x1-__uint_as_float(h1),
          l2=x2-__uint_as_float(h2), l3=x3-__uint_as_float(h3);
    lo.x = (__float_as_uint(l0)>>16) | (__float_as_uint(l1)&0xFFFF0000u);
    lo.y = (__float_as_uint(l2)>>16) | (__float_as_uint(l3)&0xFFFF0000u);
}

// Conflict-free in-LDS Cholesky + triangular inversion of a 128x128 block.
// Pre: T filled (full block), barrier done.  Post: T lower+diag = inv(chol(T)),
// upper = junk.  Ends with a barrier.
__device__ void chol_invert_lds(float T[NB][NB], int tid){
    // ---- Cholesky (right-looking) ----
    for (int j = 0; j < NB; j++){
        float d = TT(j,j);                 // broadcast (same addr all lanes)
        float inv = 1.0f / sqrtf(d);
        for (int i = j+1+tid; i < NB; i += 256) TT(i,j) *= inv;  // stride-1
        if (tid == 0) TT(j,j) = d * inv;   // = sqrt(d)
        __syncthreads();
        // rank-1 on lower triangle: thread=(row, parity); shared-k per half:
        // TT(k,j) = 2-address broadcast, TT(i,k) stride-1 (2-way, free)
        int i = j+1 + (tid >> 1);
        if (i < NB){
            float lij = TT(i,j);
            for (int k = j+1+(tid&1); k <= i; k += 2)
                TT(i,k) -= lij * TT(k,j);
        }
        __syncthreads();
    }
    // ---- in-place lower-triangular inversion ----
    // X[i][j] = -1/Lii * sum_{k=j..i-1} L[i][k] X[k][j]; rows <i already X.
    // Lane j, split halves by parity of shared descending k:
    // TT(i,k) = broadcast, TT(k,j) stride-1.  Partial of hi half staged in
    // upper-junk scratch TT(j,i).
    for (int i = 0; i < NB; i++){
        float inv_ii = 1.0f / TT(i,i);
        int j = tid & 127, hi = tid >> 7;
        float S = 0.0f;
        if (j < i){
            for (int k = i-1-hi; k >= j; k -= 2)
                S += TT(i,k) * TT(k,j);
        }
        if (hi && j < i) TT(j,i) = S;      // strictly-upper scratch, no alias
        __syncthreads();
        if (!hi){
            if (j < i)      TT(i,j) = -inv_ii * (S + TT(j,i));
            else if (j == i) TT(i,i) = inv_ii;
        }
        __syncthreads();
    }
}

// ---- f32 vector-GEMM core ----

__device__ __forceinline__ void load_tileT(float Ts[32][NB+PAD], const float* __restrict__ S,
                                           int lds_, int tid){
    int k4 = (tid & 7) * 4, c0 = tid >> 3;
    #pragma unroll
    for (int cc = c0; cc < NB; cc += 32){
        float4 v = *(const float4*)&S[(size_t)cc*lds_ + k4];
        Ts[k4+0][cc] = v.x; Ts[k4+1][cc] = v.y; Ts[k4+2][cc] = v.z; Ts[k4+3][cc] = v.w;
    }
}

__device__ __forceinline__ void load_tileS(float Ts[32][NB+PAD], const float* __restrict__ S,
                                           int lds_, int tid){
    int c4 = (tid & 31) * 4, kk = tid >> 5;
    #pragma unroll
    for (int k = kk; k < 32; k += 8){
        float4 v = *(const float4*)&S[(size_t)k*lds_ + c4];
        *(float4*)&Ts[k][c4] = v;
    }
}

__device__ __forceinline__ void mm32(const float As[32][NB+PAD], const float Bs[32][NB+PAD],
                                     int r0, int ca, int cb, float acc[8][8]){
    #pragma unroll 8
    for (int k = 0; k < 32; k++){
        float4 a0 = *(const float4*)&As[k][r0];
        float4 a1 = *(const float4*)&As[k][r0+4];
        float4 b0 = *(const float4*)&Bs[k][ca];
        float4 b1 = *(const float4*)&Bs[k][cb];
        float a[8] = {a0.x,a0.y,a0.z,a0.w,a1.x,a1.y,a1.z,a1.w};
        float b[8] = {b0.x,b0.y,b0.z,b0.w,b1.x,b1.y,b1.z,b1.w};
        #pragma unroll
        for (int u=0;u<8;u++)
            #pragma unroll
            for (int v=0;v<8;v++)
                acc[u][v] += a[u]*b[v];
    }
}

__device__ __forceinline__ void gemm_core(const float* __restrict__ A, int lda,
                                          const float* __restrict__ B, int ldb,
                                          int klen, bool bT, float acc[8][8],
                                          float As[32][NB+PAD], float Bs[32][NB+PAD])
{
    int tid = threadIdx.x;
    int r0 = (tid >> 4) * 8, ca = (tid & 15) * 4, cb = 64 + ca;
    for (int k0 = 0; k0 < klen; k0 += 32){
        load_tileT(As, A + k0, lda, tid);
        if (bT) load_tileT(Bs, B + k0, ldb, tid);
        else    load_tileS(Bs, B + (size_t)k0*ldb, ldb, tid);
        __syncthreads();
        mm32(As, Bs, r0, ca, cb, acc);
        __syncthreads();
    }
}

__device__ __forceinline__ void store_acc(float* __restrict__ Cp, int ldc,
                                          const float acc[8][8], float sgn){
    int tid = threadIdx.x;
    int r0 = (tid >> 4) * 8, ca = (tid & 15) * 4, cb = 64 + ca;
    #pragma unroll
    for (int u=0;u<8;u++){
        float4 v0 = make_float4(sgn*acc[u][0], sgn*acc[u][1], sgn*acc[u][2], sgn*acc[u][3]);
        float4 v1 = make_float4(sgn*acc[u][4], sgn*acc[u][5], sgn*acc[u][6], sgn*acc[u][7]);
        *(float4*)&Cp[(size_t)(r0+u)*ldc + ca] = v0;
        *(float4*)&Cp[(size_t)(r0+u)*ldc + cb] = v1;
    }
}

struct SmGemm { float As[32][NB+PAD]; float Bs[32][NB+PAD]; };
union SmU { SmGemm g; float T[NB][NB]; };   // 64 KiB exactly

// ---------------- kernels ----------------

__global__ void k_init_acc(float* __restrict__ acc){
    int i = blockIdx.x*blockDim.x + threadIdx.x;
    if (i < 2*M) acc[i] = 0.0f;
}

// d2te[j][i] = ||Xte_j - Xtr_i||^2   (M x N)
__global__ void k_build_d2te(const float* __restrict__ Xtr, const float* __restrict__ Xte,
                             float* __restrict__ d2){
    int j = blockIdx.x;
    float4 xj = ((const float4*)Xte)[j];
    for (int i = threadIdx.x; i < N; i += blockDim.x){
        float4 xi = ((const float4*)Xtr)[i];
        d2[(size_t)j*N + i] = sqdist4(xi,xj);
    }
}

// Build packed lower-tri blocks of K_noisy. grid (NBLK, g)
__global__ __launch_bounds__(256) void k_build_K(const float* __restrict__ Xtr,
                          const float* __restrict__ ls,
                          const float* __restrict__ var, const float* __restrict__ noise,
                          float* __restrict__ Lbuf){
    __shared__ float4 xr[NB], xc[NB];
    int c = blockIdx.y, flat = blockIdx.x;
    int ib = 0; while ((ib+1)*(ib+2)/2 <= flat) ib++;
    int jt = flat - ib*(ib+1)/2;
    int tid = threadIdx.x;
    if (tid < NB) xr[tid] = ((const float4*)Xtr)[ib*NB + tid];
    else          xc[tid-NB] = ((const float4*)Xtr)[jt*NB + (tid-NB)];
    __syncthreads();
    float il2 = 1.0f/(ls[c]*ls[c]);
    float vc = var[c], nc = noise[c];
    float* blk = Lbuf + c*PL + pblk(ib,jt);
    for (int idx = tid; idx < NB*NB; idx += 256){
        int r = idx >> 7, col = idx & 127;
        float d2v = sqdist4(xr[r], xc[col]);
        float v = vc*__expf(-0.5f*d2v*il2);
        if (ib==jt && r==col) v += nc;
        blk[idx] = v;
    }
}

// standalone factor+invert of diag block (0,0) only
__global__ __launch_bounds__(256) void k_diagF(float* __restrict__ Lbuf){
    __shared__ float T[NB][NB];
    int c = blockIdx.x, tid = threadIdx.x;
    float* A = Lbuf + c*PL + pblk(0,0);
    for (int idx = tid; idx < NB*NB; idx += 256){
        int r = idx >> 7, col = idx & 127;
        TT(r,col) = A[idx];
    }
    __syncthreads();
    chol_invert_lds(T, tid);
    for (int idx = tid; idx < NB*NB; idx += 256){
        int r = idx >> 7, col = idx & 127;
        A[idx] = (col <= r) ? TT(r,col) : 0.0f;
    }
}

// panel TRSM as GEMM: L[ib,kb] = L[ib,kb] @ Dinv_kb^T  (Dinv = packed diag kb)
__global__ __launch_bounds__(256) void k_panel(float* __restrict__ Lbuf, int kb){
    __shared__ float As[32][NB+PAD];
    __shared__ float Bs[32][NB+PAD];
    int c = blockIdx.x;
    int ib = kb + 1 + blockIdx.y;
    float* base = Lbuf + c*PL;
    float* Ablk = base + pblk(ib,kb);
    const float* Dv = base + pblk(kb,kb);
    float acc[8][8] = {};
    gemm_core(Ablk, NB, Dv, NB, NB, true, acc, As, Bs);
    store_acc(Ablk, NB, acc, 1.0f);
}

// trailing update K[i,j] -= P_i @ P_j^T; the (kb+1,kb+1) block (flat==0)
// additionally factors+inverts itself in LDS (lookahead fusion).
__global__ __launch_bounds__(256) void k_syrk(float* __restrict__ Lbuf, int kb){
    __shared__ SmU sm;
    int c = blockIdx.x;
    int flat = blockIdx.y;
    int di = 0; while ((di+1)*(di+2)/2 <= flat) di++;
    int dj = flat - di*(di+1)/2;
    int i = kb+1+di, j = kb+1+dj;
    float* base = Lbuf + c*PL;
    float* Cblk = base + pblk(i,j);
    const float* Ablk = base + pblk(i,kb);
    const float* Bblk = base + pblk(j,kb);
    float acc[8][8] = {};
    gemm_core(Ablk, NB, Bblk, NB, NB, true, acc, sm.g.As, sm.g.Bs);
    int tid = threadIdx.x;
    int r0 = (tid >> 4) * 8, ca = (tid & 15) * 4, cb = 64 + ca;
    if (flat != 0){
        #pragma unroll
        for (int u=0;u<8;u++){
            float4 c0v = *(float4*)&Cblk[(size_t)(r0+u)*NB + ca];
            float4 c1v = *(float4*)&Cblk[(size_t)(r0+u)*NB + cb];
            c0v.x -= acc[u][0]; c0v.y -= acc[u][1]; c0v.z -= acc[u][2]; c0v.w -= acc[u][3];
            c1v.x -= acc[u][4]; c1v.y -= acc[u][5]; c1v.z -= acc[u][6]; c1v.w -= acc[u][7];
            *(float4*)&Cblk[(size_t)(r0+u)*NB + ca] = c0v;
            *(float4*)&Cblk[(size_t)(r0+u)*NB + cb] = c1v;
        }
    } else {
        // stage updated diag block into T (gemm_core ended with a barrier)
        float (*T)[NB] = sm.T;
        #pragma unroll
        for (int u=0;u<8;u++){
            float4 c0v = *(const float4*)&Cblk[(size_t)(r0+u)*NB + ca];
            float4 c1v = *(const float4*)&Cblk[(size_t)(r0+u)*NB + cb];
            TT(r0+u, ca+0) = c0v.x - acc[u][0];
            TT(r0+u, ca+1) = c0v.y - acc[u][1];
            TT(r0+u, ca+2) = c0v.z - acc[u][2];
            TT(r0+u, ca+3) = c0v.w - acc[u][3];
            TT(r0+u, cb+0) = c1v.x - acc[u][4];
            TT(r0+u, cb+1) = c1v.y - acc[u][5];
            TT(r0+u, cb+2) = c1v.z - acc[u][6];
            TT(r0+u, cb+3) = c1v.w - acc[u][7];
        }
        __syncthreads();
        chol_invert_lds(T, tid);
        for (int idx = tid; idx < NB*NB; idx += 256){
            int r = idx >> 7, col = idx & 127;
            Cblk[idx] = (col <= r) ? TT(r,col) : 0.0f;
        }
    }
}

// G(ct) = Dinv_ib @ L[ib,ct]   (Dinv from packed diag ib; writes Trow [NB][N])
__global__ __launch_bounds__(256) void k_gemmA(float* __restrict__ Trow,
                                               const float* __restrict__ Lbuf, int ib){
    __shared__ float As[32][NB+PAD];
    __shared__ float Bs[32][NB+PAD];
    int c = blockIdx.x, ct = blockIdx.y;
    const float* base = Lbuf + c*PL;
    const float* Dv = base + pblk(ib,ib);
    const float* Bsrc = base + pblk(ib,ct);
    float acc[8][8] = {};
    gemm_core(Dv, NB, Bsrc, NB, NB, false, acc, As, Bs);
    store_acc(Trow + (size_t)c*NB*N + ct*NB, N, acc, 1.0f);
}

// W[ib,jt] = - sum_{kt=jt..ib-1} G[:,kt] @ W[kt,jt]   (packed)
__global__ __launch_bounds__(256) void k_gemmB(float* __restrict__ Lbuf,
                                               const float* __restrict__ Trow, int ib){
    __shared__ float As[32][NB+PAD];
    __shared__ float Bs[32][NB+PAD];
    int c = blockIdx.x, jt = blockIdx.y;
    const float* G = Trow + (size_t)c*NB*N;
    float* base = Lbuf + c*PL;
    float acc[8][8] = {};
    for (int kt = jt; kt < ib; kt++)
        gemm_core(G + kt*NB, N, base + pblk(kt,jt), NB, NB, false, acc, As, Bs);
    store_acc(base + pblk(ib,jt), NB, acc, -1.0f);
}

// z[c] = W y  (triangular matvec over packed blocks)
__global__ void k_zvec(const float* __restrict__ Lbuf, const float* __restrict__ y,
                       float* __restrict__ z){
    int c = blockIdx.x;
    int p = blockIdx.y * 4 + (threadIdx.x >> 6);
    int lane = threadIdx.x & 63;
    int pb = p >> 7, pl = p & 127;
    const float* base = Lbuf + c*PL;
    float s = 0.0f;
    for (int kt = 0; kt <= pb; kt++){
        const float* row = base + pblk(pb,kt) + (size_t)pl*NB;
        int lim = (kt==pb) ? pl : NB-1;
        for (int i = lane; i <= lim; i += 64) s += row[i]*y[kt*NB + i];
    }
    for (int off = 32; off; off >>= 1) s += __shfl_down(s, off);
    if (lane == 0) z[c*N + p] = s;
}

// Fused A = Kte @ W^T via split-bf16 MFMA; rowwise mean/var reduction.
__global__ __launch_bounds__(256) void k_bigg(const float* __restrict__ Lbuf,
                                              const float* __restrict__ d2,   // [M][N]
                                              const float* __restrict__ zbuf,
                                              const float* __restrict__ ls,
                                              const float* __restrict__ var,
                                              float* __restrict__ acc_out){
    __shared__ unsigned short Ah[NB][TP], Al[NB][TP], Bh[NB][TP], Bl[NB][TP];
    int jt = blockIdx.x, pt = blockIdx.y, c = blockIdx.z;
    int tid = threadIdx.x;
    int lane = tid & 63, w = tid >> 6;
    int wrow = w >> 1, wcol = w & 1;
    float il2 = 1.0f/(ls[c]*ls[c]);
    float vc = var[c];
    float ec = -0.5f*il2;
    const float* Arow = d2 + (size_t)(jt*NB)*N;
    const float* Wbase = Lbuf + c*PL;
    int klen = (pt+1)*NB;
    f32x4 acc[4][4];
    #pragma unroll
    for (int i=0;i<4;i++)
        #pragma unroll
        for (int j=0;j<4;j++) acc[i][j] = (f32x4)0.0f;

    int q = tid & 7, rs = tid >> 3;
    int fr = lane & 15, kg = lane >> 4;
    int ar = wrow*64 + fr, br = wcol*64 + fr;
    int kc = kg * 8;

    for (int k0 = 0; k0 < klen; k0 += 32){
        const float* Bp = Wbase + pblk(pt, k0 >> 7);
        int kloc = k0 & 127;
        __syncthreads();
        #pragma unroll
        for (int p = 0; p < 4; p++){
            int r = rs + 32*p;
            float4 dv = *(const float4*)&Arow[(size_t)r*N + k0 + q*4];
            float x0 = vc*__expf(ec*dv.x), x1 = vc*__expf(ec*dv.y);
            float x2 = vc*__expf(ec*dv.z), x3 = vc*__expf(ec*dv.w);
            uint2 hi, lo; split4(x0,x1,x2,x3, hi, lo);
            *(uint2*)&Ah[r][q*4] = hi;
            *(uint2*)&Al[r][q*4] = lo;
        }
        #pragma unroll
        for (int p = 0; p < 4; p++){
            int r = rs + 32*p;
            float4 wv = *(const float4*)&Bp[(size_t)r*NB + kloc + q*4];
            uint2 hi, lo; split4(wv.x,wv.y,wv.z,wv.w, hi, lo);
            *(uint2*)&Bh[r][q*4] = hi;
            *(uint2*)&Bl[r][q*4] = lo;
        }
        __syncthreads();
        bf16x8 ah[4], al[4];
        #pragma unroll
        for (int rt=0;rt<4;rt++){
            ah[rt] = *(const bf16x8*)&Ah[ar + rt*16][kc];
            al[rt] = *(const bf16x8*)&Al[ar + rt*16][kc];
        }
        #pragma unroll
        for (int ct=0;ct<4;ct++){
            bf16x8 bh = *(const bf16x8*)&Bh[br + ct*16][kc];
            bf16x8 bl = *(const bf16x8*)&Bl[br + ct*16][kc];
            #pragma unroll
            for (int rt=0;rt<4;rt++){
                f32x4 a = acc[rt][ct];
                a = __builtin_amdgcn_mfma_f32_16x16x32_bf16(ah[rt], bh, a, 0,0,0);
                a = __builtin_amdgcn_mfma_f32_16x16x32_bf16(ah[rt], bl, a, 0,0,0);
                a = __builtin_amdgcn_mfma_f32_16x16x32_bf16(al[rt], bh, a, 0,0,0);
                acc[rt][ct] = a;
            }
        }
    }
    float zv[4];
    #pragma unroll
    for (int ct=0;ct<4;ct++) zv[ct] = zbuf[c*N + pt*NB + wcol*64 + ct*16 + fr];
    #pragma unroll
    for (int rt=0;rt<4;rt++){
        #pragma unroll
        for (int r=0;r<4;r++){
            float m = 0.0f, v = 0.0f;
            #pragma unroll
            for (int ct=0;ct<4;ct++){
                float x = acc[rt][ct][r];
                v += x*x; m += x*zv[ct];
            }
            m += __shfl_xor(m, 1);  v += __shfl_xor(v, 1);
            m += __shfl_xor(m, 2);  v += __shfl_xor(v, 2);
            m += __shfl_xor(m, 4);  v += __shfl_xor(v, 4);
            m += __shfl_xor(m, 8);  v += __shfl_xor(v, 8);
            if (fr == 0){
                int j = jt*NB + wrow*64 + rt*16 + kg*4 + r;
                atomicAdd(&acc_out[j], m);
                atomicAdd(&acc_out[M + j], v);
            }
        }
    }
}

__global__ void k_final(const float* __restrict__ acc, float* __restrict__ out){
    int i = blockIdx.x*blockDim.x + threadIdx.x;
    if (i < 2*M) out[i] = acc[i] * (1.0f/64.0f);
}

// ---------------- launch ----------------
// per-chain ws = packed-L + Trow + z  (Dinv eliminated)

extern "C" void kernel_launch(void* const* d_in, const int* in_sizes, int n_in,
                              void* d_out, int out_size, void* d_ws, size_t ws_size,
                              hipStream_t stream) {
    const float* Xtr = (const float*)d_in[0];
    const float* ytr = (const float*)d_in[1];
    const float* Xte = (const float*)d_in[2];
    const float* ls  = (const float*)d_in[3];
    const float* var = (const float*)d_in[4];
    const float* noi = (const float*)d_in[5];
    float* out = (float*)d_out;

    float* ws = (float*)d_ws;
    const size_t shared_fl  = (size_t)N*M + 2*M;              // d2te + acc
    const size_t perchain   = PL + (size_t)NB*N + (size_t)N;  // L + Trow + z
    size_t avail = ws_size / sizeof(float);
    if (avail < shared_fl + perchain) return;
    int Gmax = (int)((avail - shared_fl) / perchain);
    if (Gmax > C) Gmax = C;
    int nbatch = (C + Gmax - 1) / Gmax;
    int G = (C + nbatch - 1) / nbatch;          // balanced batches

    float* d2te = ws;
    float* acc  = d2te + (size_t)N*M;
    float* Lbuf = acc  + 2*M;
    float* Trow = Lbuf + (size_t)G*PL;
    float* zbuf = Trow + (size_t)G*NB*N;

    k_init_acc<<<dim3((2*M+255)/256), dim3(256), 0, stream>>>(acc);
    k_build_d2te<<<dim3(M), dim3(256), 0, stream>>>(Xtr, Xte, d2te);

    for (int c0 = 0; c0 < C; c0 += G){
        int g = C - c0 < G ? C - c0 : G;

        k_build_K<<<dim3(NBLK, g), dim3(256), 0, stream>>>(Xtr, ls+c0, var+c0, noi+c0, Lbuf);
        k_diagF<<<dim3(g), dim3(256), 0, stream>>>(Lbuf);

        for (int kb = 0; kb < TB-1; kb++){
            int rem = TB-1-kb;
            k_panel<<<dim3(g, rem), dim3(256), 0, stream>>>(Lbuf, kb);
            k_syrk<<<dim3(g, rem*(rem+1)/2), dim3(256), 0, stream>>>(Lbuf, kb);
        }
        for (int ib = 1; ib < TB; ib++){
            k_gemmA<<<dim3(g, ib), dim3(256), 0, stream>>>(Trow, Lbuf, ib);
            k_gemmB<<<dim3(g, ib), dim3(256), 0, stream>>>(Lbuf, Trow, ib);
        }
        k_zvec<<<dim3(g, N/4), dim3(256), 0, stream>>>(Lbuf, ytr, zbuf);
        k_bigg<<<dim3(M/NB, TB, g), dim3(256), 0, stream>>>(Lbuf, d2te, zbuf, ls+c0, var+c0, acc);
    }
    k_final<<<dim3((2*M+255)/256), dim3(256), 0, stream>>>(acc, out);
}

// Round 7
// 5540.621 us; speedup vs baseline: 3.1895x; 1.1213x over previous
//
#include <hip/hip_runtime.h>
#include <hip/hip_fp16.h>
#include <math.h>

#define N 1024
#define M 2048
#define C 64
#define NB 128
#define TB 8    // N/NB
#define NBLK 36                   // TB*(TB+1)/2 lower-tri blocks
#define PL ((size_t)NBLK*NB*NB)   // packed L floats per chain

typedef __attribute__((ext_vector_type(8))) short bf16x8;
typedef __attribute__((ext_vector_type(8))) _Float16 f16x8;
typedef __attribute__((ext_vector_type(4))) float f32x4;

__device__ __forceinline__ size_t pblk(int ib, int jt){
    return ((size_t)((ib*(ib+1))/2 + jt))*((size_t)NB*NB);
}

// rotate-swizzle for the in-LDS factor: bank=(r+c)%32
#define TT(r,c) T[(r)][(((c)+(r)) & 127)]

// ---------------- helpers ----------------

__device__ __forceinline__ float sqdist4(const float4 a, const float4 b){
    float dx=a.x-b.x, dy=a.y-b.y, dz=a.z-b.z, dw=a.w-b.w;
    return dx*dx+dy*dy+dz*dz+dw*dw;
}

// split 4 floats into bf16 hi (trunc) + bf16 lo (residual), packed 2/dword
__device__ __forceinline__ void split4(float x0, float x1, float x2, float x3,
                                       uint2& hi, uint2& lo){
    unsigned b0=__float_as_uint(x0), b1=__float_as_uint(x1),
             b2=__float_as_uint(x2), b3=__float_as_uint(x3);
    unsigned h0=b0&0xFFFF0000u, h1=b1&0xFFFF0000u, h2=b2&0xFFFF0000u, h3=b3&0xFFFF0000u;
    hi.x = (h0>>16)|h1;  hi.y = (h2>>16)|h3;
    float l0=x0-__uint_as_float(h0), l1=x1-__uint_as_float(h1),
          l2=x2-__uint_as_float(h2), l3=x3-__uint_as_float(h3);
    lo.x = (__float_as_uint(l0)>>16) | (__float_as_uint(l1)&0xFFFF0000u);
    lo.y = (__float_as_uint(l2)>>16) | (__float_as_uint(l3)&0xFFFF0000u);
}

// Conflict-free in-LDS Cholesky + triangular inversion of a 128x128 block.
__device__ void chol_invert_lds(float T[NB][NB], int tid){
    for (int j = 0; j < NB; j++){
        float d = TT(j,j);
        float inv = 1.0f / sqrtf(d);
        for (int i = j+1+tid; i < NB; i += 256) TT(i,j) *= inv;
        if (tid == 0) TT(j,j) = d * inv;
        __syncthreads();
        int i = j+1 + (tid >> 1);
        if (i < NB){
            float lij = TT(i,j);
            for (int k = j+1+(tid&1); k <= i; k += 2)
                TT(i,k) -= lij * TT(k,j);
        }
        __syncthreads();
    }
    for (int i = 0; i < NB; i++){
        float inv_ii = 1.0f / TT(i,i);
        int j = tid & 127, hi = tid >> 7;
        float S = 0.0f;
        if (j < i){
            for (int k = i-1-hi; k >= j; k -= 2)
                S += TT(i,k) * TT(k,j);
        }
        if (hi && j < i) TT(j,i) = S;
        __syncthreads();
        if (!hi){
            if (j < i)      TT(i,j) = -inv_ii * (S + TT(j,i));
            else if (j == i) TT(i,i) = inv_ii;
        }
        __syncthreads();
    }
}

// ---------------- split-f16 MFMA 128x128x128 GEMM core ----------------
// Fragment-order LDS: unit u=(half,rt,kg,fr) at u*16B; wave reads lane*16B.

struct FragLds { __half Ah[4096], Al[4096], Bh[4096], Bl[4096]; }; // 32 KiB

// Stage one 32-k slab. contig: S[rc][k] row-major; else S[k][rc] (strided).
__device__ __forceinline__ void stage_f16(__half* __restrict__ Hh, __half* __restrict__ Hl,
                                          const float* __restrict__ S, int ld,
                                          int k0, bool contig, int tid){
    #pragma unroll
    for (int h = 0; h < 2; h++){
        int u = tid + h*256;
        int fr = u & 15, kg = (u>>4)&3, rt = (u>>6)&3, hf = u>>8;
        int rc = hf*64 + rt*16 + fr;
        int kk = k0 + kg*8;
        float x[8];
        if (contig){
            float4 v0 = *(const float4*)&S[(size_t)rc*ld + kk];
            float4 v1 = *(const float4*)&S[(size_t)rc*ld + kk + 4];
            x[0]=v0.x;x[1]=v0.y;x[2]=v0.z;x[3]=v0.w;
            x[4]=v1.x;x[5]=v1.y;x[6]=v1.z;x[7]=v1.w;
        } else {
            #pragma unroll
            for (int e=0;e<8;e++) x[e] = S[(size_t)(kk+e)*ld + rc];
        }
        union { __half h[8]; uint4 u4; } Hi, Lo;
        #pragma unroll
        for (int e=0;e<8;e++){
            __half hv = __float2half_rn(x[e]);
            Hi.h[e] = hv;
            Lo.h[e] = __float2half_rn(x[e] - __half2float(hv));
        }
        *(uint4*)&Hh[(size_t)u*8] = Hi.u4;
        *(uint4*)&Hl[(size_t)u*8] = Lo.u4;
    }
}

__device__ __forceinline__ void mfma_slab_f16(const __half* Ah, const __half* Al,
                                              const __half* Bh, const __half* Bl,
                                              int wrow, int wcol, int lane,
                                              f32x4 acc[4][4]){
    f16x8 ah[4], al[4];
    #pragma unroll
    for (int rt=0;rt<4;rt++){
        ah[rt] = *(const f16x8*)&Ah[((size_t)((wrow*4+rt)*64 + lane))*8];
        al[rt] = *(const f16x8*)&Al[((size_t)((wrow*4+rt)*64 + lane))*8];
    }
    #pragma unroll
    for (int ct=0;ct<4;ct++){
        f16x8 bh = *(const f16x8*)&Bh[((size_t)((wcol*4+ct)*64 + lane))*8];
        f16x8 bl = *(const f16x8*)&Bl[((size_t)((wcol*4+ct)*64 + lane))*8];
        #pragma unroll
        for (int rt=0;rt<4;rt++){
            f32x4 a = acc[rt][ct];
            a = __builtin_amdgcn_mfma_f32_16x16x32_f16(ah[rt], bh, a, 0,0,0);
            a = __builtin_amdgcn_mfma_f32_16x16x32_f16(ah[rt], bl, a, 0,0,0);
            a = __builtin_amdgcn_mfma_f32_16x16x32_f16(al[rt], bh, a, 0,0,0);
            acc[rt][ct] = a;
        }
    }
}

// C128 += A(128xK=128, row-major lda) @ B; bContig: B[c][k] (B^T layout); else B[k][c].
__device__ void gemm_f16_unit(const float* __restrict__ A, int lda,
                              const float* __restrict__ B, int ldb, bool bContig,
                              FragLds& F, f32x4 acc[4][4], int tid){
    int lane = tid & 63, w = tid >> 6, wrow = w>>1, wcol = w&1;
    for (int k0 = 0; k0 < NB; k0 += 32){
        __syncthreads();
        stage_f16(F.Ah, F.Al, A, lda, k0, true, tid);
        stage_f16(F.Bh, F.Bl, B, ldb, k0, bContig, tid);
        __syncthreads();
        mfma_slab_f16(F.Ah, F.Al, F.Bh, F.Bl, wrow, wcol, lane, acc);
    }
}

// D-layout store: row = wrow*64+rt*16+kg*4+r, col = wcol*64+ct*16+fr
__device__ __forceinline__ void store_f16acc(float* __restrict__ Cp, int ldc,
                                             const f32x4 acc[4][4], float sgn, int tid){
    int lane = tid&63, w = tid>>6, wrow = w>>1, wcol = w&1;
    int fr = lane&15, kg = lane>>4;
    #pragma unroll
    for (int rt=0;rt<4;rt++)
      #pragma unroll
      for (int ct=0;ct<4;ct++)
        #pragma unroll
        for (int r=0;r<4;r++){
            int row = wrow*64 + rt*16 + kg*4 + r;
            int col = wcol*64 + ct*16 + fr;
            Cp[(size_t)row*ldc + col] = sgn*acc[rt][ct][r];
        }
}

#define ZERO_ACC(acc) { _Pragma("unroll") for (int zi=0;zi<4;zi++) _Pragma("unroll") for (int zj=0;zj<4;zj++) acc[zi][zj] = (f32x4)0.0f; }

// ---------------- kernels ----------------

__global__ void k_init_acc(float* __restrict__ acc){
    int i = blockIdx.x*blockDim.x + threadIdx.x;
    if (i < 2*M) acc[i] = 0.0f;
}

// d2te[j][i] = ||Xte_j - Xtr_i||^2   (M x N)
__global__ void k_build_d2te(const float* __restrict__ Xtr, const float* __restrict__ Xte,
                             float* __restrict__ d2){
    int j = blockIdx.x;
    float4 xj = ((const float4*)Xte)[j];
    for (int i = threadIdx.x; i < N; i += blockDim.x){
        float4 xi = ((const float4*)Xtr)[i];
        d2[(size_t)j*N + i] = sqdist4(xi,xj);
    }
}

// Build packed lower-tri blocks of K_noisy. grid (NBLK, g)
__global__ __launch_bounds__(256) void k_build_K(const float* __restrict__ Xtr,
                          const float* __restrict__ ls,
                          const float* __restrict__ var, const float* __restrict__ noise,
                          float* __restrict__ Lbuf){
    __shared__ float4 xr[NB], xc[NB];
    int c = blockIdx.y, flat = blockIdx.x;
    int ib = 0; while ((ib+1)*(ib+2)/2 <= flat) ib++;
    int jt = flat - ib*(ib+1)/2;
    int tid = threadIdx.x;
    if (tid < NB) xr[tid] = ((const float4*)Xtr)[ib*NB + tid];
    else          xc[tid-NB] = ((const float4*)Xtr)[jt*NB + (tid-NB)];
    __syncthreads();
    float il2 = 1.0f/(ls[c]*ls[c]);
    float vc = var[c], nc = noise[c];
    float* blk = Lbuf + c*PL + pblk(ib,jt);
    for (int idx = tid; idx < NB*NB; idx += 256){
        int r = idx >> 7, col = idx & 127;
        float d2v = sqdist4(xr[r], xc[col]);
        float v = vc*__expf(-0.5f*d2v*il2);
        if (ib==jt && r==col) v += nc;
        blk[idx] = v;
    }
}

// standalone factor+invert of diag block (0,0)
__global__ __launch_bounds__(256) void k_diagF(float* __restrict__ Lbuf){
    __shared__ float T[NB][NB];
    int c = blockIdx.x, tid = threadIdx.x;
    float* A = Lbuf + c*PL + pblk(0,0);
    for (int idx = tid; idx < NB*NB; idx += 256){
        int r = idx >> 7, col = idx & 127;
        TT(r,col) = A[idx];
    }
    __syncthreads();
    chol_invert_lds(T, tid);
    for (int idx = tid; idx < NB*NB; idx += 256){
        int r = idx >> 7, col = idx & 127;
        A[idx] = (col <= r) ? TT(r,col) : 0.0f;
    }
}

// panel TRSM as GEMM: L[ib,kb] = L[ib,kb] @ Dinv_kb^T   (split-f16 MFMA, in place)
__global__ __launch_bounds__(256) void k_panel(float* __restrict__ Lbuf, int kb){
    __shared__ FragLds F;
    int c = blockIdx.x;
    int ib = kb + 1 + blockIdx.y;
    int tid = threadIdx.x;
    float* base = Lbuf + c*PL;
    float* Ablk = base + pblk(ib,kb);
    const float* Dv = base + pblk(kb,kb);
    f32x4 acc[4][4]; ZERO_ACC(acc);
    gemm_f16_unit(Ablk, NB, Dv, NB, true, F, acc, tid);   // B[c][k]=Dinv[c][k]
    store_f16acc(Ablk, NB, acc, 1.0f, tid);
}

// trailing update K[i,j] -= P_i @ P_j^T; flat==0 block also factors+inverts
union SmU2 { FragLds f; float T[NB][NB]; };   // 64 KiB
__global__ __launch_bounds__(256) void k_syrk(float* __restrict__ Lbuf, int kb){
    __shared__ SmU2 sm;
    int c = blockIdx.x;
    int flat = blockIdx.y;
    int di = 0; while ((di+1)*(di+2)/2 <= flat) di++;
    int dj = flat - di*(di+1)/2;
    int i = kb+1+di, j = kb+1+dj;
    int tid = threadIdx.x;
    float* base = Lbuf + c*PL;
    float* Cblk = base + pblk(i,j);
    const float* Ablk = base + pblk(i,kb);
    const float* Bblk = base + pblk(j,kb);
    f32x4 acc[4][4]; ZERO_ACC(acc);
    gemm_f16_unit(Ablk, NB, Bblk, NB, true, sm.f, acc, tid);  // B[c][k]=L[j,kb][c][k]
    int lane = tid&63, w = tid>>6, wrow = w>>1, wcol = w&1;
    int fr = lane&15, kg = lane>>4;
    if (flat != 0){
        #pragma unroll
        for (int rt=0;rt<4;rt++)
          #pragma unroll
          for (int ct=0;ct<4;ct++)
            #pragma unroll
            for (int r=0;r<4;r++){
                int row = wrow*64 + rt*16 + kg*4 + r;
                int col = wcol*64 + ct*16 + fr;
                Cblk[(size_t)row*NB + col] -= acc[rt][ct][r];
            }
    } else {
        __syncthreads();   // frag LDS reads done; safe to reuse as T
        float (*T)[NB] = sm.T;
        #pragma unroll
        for (int rt=0;rt<4;rt++)
          #pragma unroll
          for (int ct=0;ct<4;ct++)
            #pragma unroll
            for (int r=0;r<4;r++){
                int row = wrow*64 + rt*16 + kg*4 + r;
                int col = wcol*64 + ct*16 + fr;
                TT(row,col) = Cblk[(size_t)row*NB + col] - acc[rt][ct][r];
            }
        __syncthreads();
        chol_invert_lds(T, tid);
        for (int idx = tid; idx < NB*NB; idx += 256){
            int r = idx >> 7, col = idx & 127;
            Cblk[idx] = (col <= r) ? TT(r,col) : 0.0f;
        }
    }
}

// G(ct) = Dinv_ib @ L[ib,ct]   (split-f16 MFMA; writes Trow [NB][N])
__global__ __launch_bounds__(256) void k_gemmA(float* __restrict__ Trow,
                                               const float* __restrict__ Lbuf, int ib){
    __shared__ FragLds F;
    int c = blockIdx.x, ct = blockIdx.y;
    int tid = threadIdx.x;
    const float* base = Lbuf + c*PL;
    const float* Dv = base + pblk(ib,ib);
    const float* Bsrc = base + pblk(ib,ct);
    f32x4 acc[4][4]; ZERO_ACC(acc);
    gemm_f16_unit(Dv, NB, Bsrc, NB, false, F, acc, tid);  // B[k][c] strided
    store_f16acc(Trow + (size_t)c*NB*N + ct*NB, N, acc, 1.0f, tid);
}

// W[ib,jt] = - sum_{kt=jt..ib-1} G[:,kt] @ W[kt,jt]   (split-f16 MFMA)
__global__ __launch_bounds__(256) void k_gemmB(float* __restrict__ Lbuf,
                                               const float* __restrict__ Trow, int ib){
    __shared__ FragLds F;
    int c = blockIdx.x, jt = blockIdx.y;
    int tid = threadIdx.x;
    const float* G = Trow + (size_t)c*NB*N;
    float* base = Lbuf + c*PL;
    f32x4 acc[4][4]; ZERO_ACC(acc);
    for (int kt = jt; kt < ib; kt++)
        gemm_f16_unit(G + kt*NB, N, base + pblk(kt,jt), NB, false, F, acc, tid);
    store_f16acc(base + pblk(ib,jt), NB, acc, -1.0f, tid);
}

// z[c] = W y  (triangular matvec over packed blocks)
__global__ void k_zvec(const float* __restrict__ Lbuf, const float* __restrict__ y,
                       float* __restrict__ z){
    int c = blockIdx.x;
    int p = blockIdx.y * 4 + (threadIdx.x >> 6);
    int lane = threadIdx.x & 63;
    int pb = p >> 7, pl = p & 127;
    const float* base = Lbuf + c*PL;
    float s = 0.0f;
    for (int kt = 0; kt <= pb; kt++){
        const float* row = base + pblk(pb,kt) + (size_t)pl*NB;
        int lim = (kt==pb) ? pl : NB-1;
        for (int i = lane; i <= lim; i += 64) s += row[i]*y[kt*NB + i];
    }
    for (int off = 32; off; off >>= 1) s += __shfl_down(s, off);
    if (lane == 0) z[c*N + p] = s;
}

// Fused A = Kte @ W^T via split-bf16 MFMA, fragment-order LDS (conflict-free).
__global__ __launch_bounds__(256) void k_bigg(const float* __restrict__ Lbuf,
                                              const float* __restrict__ d2,   // [M][N]
                                              const float* __restrict__ zbuf,
                                              const float* __restrict__ ls,
                                              const float* __restrict__ var,
                                              float* __restrict__ acc_out){
    __shared__ unsigned short Ah[4096], Al[4096], Bh[4096], Bl[4096];  // 32 KiB
    int jt = blockIdx.x, pt = blockIdx.y, c = blockIdx.z;
    int tid = threadIdx.x;
    int lane = tid & 63, w = tid >> 6;
    int wrow = w >> 1, wcol = w & 1;
    float il2 = 1.0f/(ls[c]*ls[c]);
    float vc = var[c];
    float ec = -0.5f*il2;
    const float* Arow = d2 + (size_t)(jt*NB)*N;
    const float* Wbase = Lbuf + c*PL;
    int klen = (pt+1)*NB;
    f32x4 acc[4][4]; ZERO_ACC(acc);

    int fr = lane & 15, kg = lane >> 4;

    for (int k0 = 0; k0 < klen; k0 += 32){
        const float* Bp = Wbase + pblk(pt, k0 >> 7);
        int kloc = k0 & 127;
        __syncthreads();
        #pragma unroll
        for (int h = 0; h < 2; h++){
            int u = tid + h*256;
            int ufr = u & 15, ukg = (u>>4)&3, urt = (u>>6)&3, uhf = u>>8;
            int row = uhf*64 + urt*16 + ufr;
            int kk = k0 + ukg*8;
            float4 d0 = *(const float4*)&Arow[(size_t)row*N + kk];
            float4 d1 = *(const float4*)&Arow[(size_t)row*N + kk + 4];
            float x0 = vc*__expf(ec*d0.x), x1 = vc*__expf(ec*d0.y);
            float x2 = vc*__expf(ec*d0.z), x3 = vc*__expf(ec*d0.w);
            float x4 = vc*__expf(ec*d1.x), x5 = vc*__expf(ec*d1.y);
            float x6 = vc*__expf(ec*d1.z), x7 = vc*__expf(ec*d1.w);
            uint2 h0, l0, h1, l1;
            split4(x0,x1,x2,x3, h0, l0);
            split4(x4,x5,x6,x7, h1, l1);
            *(uint4*)&Ah[(size_t)u*8] = make_uint4(h0.x,h0.y,h1.x,h1.y);
            *(uint4*)&Al[(size_t)u*8] = make_uint4(l0.x,l0.y,l1.x,l1.y);
        }
        #pragma unroll
        for (int h = 0; h < 2; h++){
            int u = tid + h*256;
            int ufr = u & 15, ukg = (u>>4)&3, urt = (u>>6)&3, uhf = u>>8;
            int p = uhf*64 + urt*16 + ufr;
            int kk = kloc + ukg*8;
            float4 w0 = *(const float4*)&Bp[(size_t)p*NB + kk];
            float4 w1 = *(const float4*)&Bp[(size_t)p*NB + kk + 4];
            uint2 h0, l0, h1, l1;
            split4(w0.x,w0.y,w0.z,w0.w, h0, l0);
            split4(w1.x,w1.y,w1.z,w1.w, h1, l1);
            *(uint4*)&Bh[(size_t)u*8] = make_uint4(h0.x,h0.y,h1.x,h1.y);
            *(uint4*)&Bl[(size_t)u*8] = make_uint4(l0.x,l0.y,l1.x,l1.y);
        }
        __syncthreads();
        bf16x8 ah[4], al[4];
        #pragma unroll
        for (int rt=0;rt<4;rt++){
            ah[rt] = *(const bf16x8*)&Ah[((size_t)((wrow*4+rt)*64 + lane))*8];
            al[rt] = *(const bf16x8*)&Al[((size_t)((wrow*4+rt)*64 + lane))*8];
        }
        #pragma unroll
        for (int ct=0;ct<4;ct++){
            bf16x8 bh = *(const bf16x8*)&Bh[((size_t)((wcol*4+ct)*64 + lane))*8];
            bf16x8 bl = *(const bf16x8*)&Bl[((size_t)((wcol*4+ct)*64 + lane))*8];
            #pragma unroll
            for (int rt=0;rt<4;rt++){
                f32x4 a = acc[rt][ct];
                a = __builtin_amdgcn_mfma_f32_16x16x32_bf16(ah[rt], bh, a, 0,0,0);
                a = __builtin_amdgcn_mfma_f32_16x16x32_bf16(ah[rt], bl, a, 0,0,0);
                a = __builtin_amdgcn_mfma_f32_16x16x32_bf16(al[rt], bh, a, 0,0,0);
                acc[rt][ct] = a;
            }
        }
    }
    float zv[4];
    #pragma unroll
    for (int ct=0;ct<4;ct++) zv[ct] = zbuf[c*N + pt*NB + wcol*64 + ct*16 + fr];
    #pragma unroll
    for (int rt=0;rt<4;rt++){
        #pragma unroll
        for (int r=0;r<4;r++){
            float m = 0.0f, v = 0.0f;
            #pragma unroll
            for (int ct=0;ct<4;ct++){
                float x = acc[rt][ct][r];
                v += x*x; m += x*zv[ct];
            }
            m += __shfl_xor(m, 1);  v += __shfl_xor(v, 1);
            m += __shfl_xor(m, 2);  v += __shfl_xor(v, 2);
            m += __shfl_xor(m, 4);  v += __shfl_xor(v, 4);
            m += __shfl_xor(m, 8);  v += __shfl_xor(v, 8);
            if (fr == 0){
                int j = jt*NB + wrow*64 + rt*16 + kg*4 + r;
                atomicAdd(&acc_out[j], m);
                atomicAdd(&acc_out[M + j], v);
            }
        }
    }
}

__global__ void k_final(const float* __restrict__ acc, float* __restrict__ out){
    int i = blockIdx.x*blockDim.x + threadIdx.x;
    if (i < 2*M) out[i] = acc[i] * (1.0f/64.0f);
}

// ---------------- launch ----------------

extern "C" void kernel_launch(void* const* d_in, const int* in_sizes, int n_in,
                              void* d_out, int out_size, void* d_ws, size_t ws_size,
                              hipStream_t stream) {
    const float* Xtr = (const float*)d_in[0];
    const float* ytr = (const float*)d_in[1];
    const float* Xte = (const float*)d_in[2];
    const float* ls  = (const float*)d_in[3];
    const float* var = (const float*)d_in[4];
    const float* noi = (const float*)d_in[5];
    float* out = (float*)d_out;

    float* ws = (float*)d_ws;
    const size_t shared_fl  = (size_t)N*M + 2*M;              // d2te + acc
    const size_t perchain   = PL + (size_t)NB*N + (size_t)N;  // L + Trow + z
    size_t avail = ws_size / sizeof(float);
    if (avail < shared_fl + perchain) return;
    int Gmax = (int)((avail - shared_fl) / perchain);
    if (Gmax > C) Gmax = C;
    int nbatch = (C + Gmax - 1) / Gmax;
    int G = (C + nbatch - 1) / nbatch;          // balanced batches

    float* d2te = ws;
    float* acc  = d2te + (size_t)N*M;
    float* Lbuf = acc  + 2*M;
    float* Trow = Lbuf + (size_t)G*PL;
    float* zbuf = Trow + (size_t)G*NB*N;

    k_init_acc<<<dim3((2*M+255)/256), dim3(256), 0, stream>>>(acc);
    k_build_d2te<<<dim3(M), dim3(256), 0, stream>>>(Xtr, Xte, d2te);

    for (int c0 = 0; c0 < C; c0 += G){
        int g = C - c0 < G ? C - c0 : G;

        k_build_K<<<dim3(NBLK, g), dim3(256), 0, stream>>>(Xtr, ls+c0, var+c0, noi+c0, Lbuf);
        k_diagF<<<dim3(g), dim3(256), 0, stream>>>(Lbuf);

        for (int kb = 0; kb < TB-1; kb++){
            int rem = TB-1-kb;
            k_panel<<<dim3(g, rem), dim3(256), 0, stream>>>(Lbuf, kb);
            k_syrk<<<dim3(g, rem*(rem+1)/2), dim3(256), 0, stream>>>(Lbuf, kb);
        }
        for (int ib = 1; ib < TB; ib++){
            k_gemmA<<<dim3(g, ib), dim3(256), 0, stream>>>(Trow, Lbuf, ib);
            k_gemmB<<<dim3(g, ib), dim3(256), 0, stream>>>(Lbuf, Trow, ib);
        }
        k_zvec<<<dim3(g, N/4), dim3(256), 0, stream>>>(Lbuf, ytr, zbuf);
        k_bigg<<<dim3(M/NB, TB, g), dim3(256), 0, stream>>>(Lbuf, d2te, zbuf, ls+c0, var+c0, acc);
    }
    k_final<<<dim3((2*M+255)/256), dim3(256), 0, stream>>>(acc, out);
}

// Round 8
// 5531.799 us; speedup vs baseline: 3.1946x; 1.0016x over previous
//
#include <hip/hip_runtime.h>
#include <hip/hip_fp16.h>
#include <math.h>

#define N 1024
#define M 2048
#define C 64
#define NB 128
#define TB 8    // N/NB
#define NBLK 36                   // TB*(TB+1)/2 lower-tri blocks
#define PL ((size_t)NBLK*NB*NB)   // packed L floats per chain

typedef __attribute__((ext_vector_type(8))) short bf16x8;
typedef __attribute__((ext_vector_type(8))) _Float16 f16x8;
typedef __attribute__((ext_vector_type(4))) float f32x4;

__device__ __forceinline__ size_t pblk(int ib, int jt){
    return ((size_t)((ib*(ib+1))/2 + jt))*((size_t)NB*NB);
}

// rotate-swizzle for the in-LDS factor: bank=(r+c)%32
#define TT(r,c) T[(r)][(((c)+(r)) & 127)]

// ---------------- helpers ----------------

__device__ __forceinline__ float sqdist4(const float4 a, const float4 b){
    float dx=a.x-b.x, dy=a.y-b.y, dz=a.z-b.z, dw=a.w-b.w;
    return dx*dx+dy*dy+dz*dz+dw*dw;
}

// split 4 floats into bf16 hi (trunc) + bf16 lo (residual), packed 2/dword
__device__ __forceinline__ void split4(float x0, float x1, float x2, float x3,
                                       uint2& hi, uint2& lo){
    unsigned b0=__float_as_uint(x0), b1=__float_as_uint(x1),
             b2=__float_as_uint(x2), b3=__float_as_uint(x3);
    unsigned h0=b0&0xFFFF0000u, h1=b1&0xFFFF0000u, h2=b2&0xFFFF0000u, h3=b3&0xFFFF0000u;
    hi.x = (h0>>16)|h1;  hi.y = (h2>>16)|h3;
    float l0=x0-__uint_as_float(h0), l1=x1-__uint_as_float(h1),
          l2=x2-__uint_as_float(h2), l3=x3-__uint_as_float(h3);
    lo.x = (__float_as_uint(l0)>>16) | (__float_as_uint(l1)&0xFFFF0000u);
    lo.y = (__float_as_uint(l2)>>16) | (__float_as_uint(l3)&0xFFFF0000u);
}

// Conflict-free in-LDS Cholesky + triangular inversion of a 128x128 block.
__device__ void chol_invert_lds(float T[NB][NB], int tid){
    for (int j = 0; j < NB; j++){
        float d = TT(j,j);
        float inv = 1.0f / sqrtf(d);
        for (int i = j+1+tid; i < NB; i += 256) TT(i,j) *= inv;
        if (tid == 0) TT(j,j) = d * inv;
        __syncthreads();
        int i = j+1 + (tid >> 1);
        if (i < NB){
            float lij = TT(i,j);
            for (int k = j+1+(tid&1); k <= i; k += 2)
                TT(i,k) -= lij * TT(k,j);
        }
        __syncthreads();
    }
    for (int i = 0; i < NB; i++){
        float inv_ii = 1.0f / TT(i,i);
        int j = tid & 127, hi = tid >> 7;
        float S = 0.0f;
        if (j < i){
            for (int k = i-1-hi; k >= j; k -= 2)
                S += TT(i,k) * TT(k,j);
        }
        if (hi && j < i) TT(j,i) = S;
        __syncthreads();
        if (!hi){
            if (j < i)      TT(i,j) = -inv_ii * (S + TT(j,i));
            else if (j == i) TT(i,i) = inv_ii;
        }
        __syncthreads();
    }
}

// ---------------- split-f16 MFMA 128x128x128 GEMM core ----------------
// Fragment-order LDS: unit u=(half,rt,kg,fr) at u*16B; wave reads lane*16B.

struct FragLds { __half Ah[4096], Al[4096], Bh[4096], Bl[4096]; }; // 32 KiB

// Stage one 32-k slab. contig: S[rc][k] row-major; else S[k][rc] (strided).
__device__ __forceinline__ void stage_f16(__half* __restrict__ Hh, __half* __restrict__ Hl,
                                          const float* __restrict__ S, int ld,
                                          int k0, bool contig, int tid){
    #pragma unroll
    for (int h = 0; h < 2; h++){
        int u = tid + h*256;
        int fr = u & 15, kg = (u>>4)&3, rt = (u>>6)&3, hf = u>>8;
        int rc = hf*64 + rt*16 + fr;
        int kk = k0 + kg*8;
        float x[8];
        if (contig){
            float4 v0 = *(const float4*)&S[(size_t)rc*ld + kk];
            float4 v1 = *(const float4*)&S[(size_t)rc*ld + kk + 4];
            x[0]=v0.x;x[1]=v0.y;x[2]=v0.z;x[3]=v0.w;
            x[4]=v1.x;x[5]=v1.y;x[6]=v1.z;x[7]=v1.w;
        } else {
            #pragma unroll
            for (int e=0;e<8;e++) x[e] = S[(size_t)(kk+e)*ld + rc];
        }
        union { __half h[8]; uint4 u4; } Hi, Lo;
        #pragma unroll
        for (int e=0;e<8;e++){
            __half hv = __float2half_rn(x[e]);
            Hi.h[e] = hv;
            Lo.h[e] = __float2half_rn(x[e] - __half2float(hv));
        }
        *(uint4*)&Hh[(size_t)u*8] = Hi.u4;
        *(uint4*)&Hl[(size_t)u*8] = Lo.u4;
    }
}

__device__ __forceinline__ void mfma_slab_f16(const __half* Ah, const __half* Al,
                                              const __half* Bh, const __half* Bl,
                                              int wrow, int wcol, int lane,
                                              f32x4 acc[4][4]){
    f16x8 ah[4], al[4];
    #pragma unroll
    for (int rt=0;rt<4;rt++){
        ah[rt] = *(const f16x8*)&Ah[((size_t)((wrow*4+rt)*64 + lane))*8];
        al[rt] = *(const f16x8*)&Al[((size_t)((wrow*4+rt)*64 + lane))*8];
    }
    #pragma unroll
    for (int ct=0;ct<4;ct++){
        f16x8 bh = *(const f16x8*)&Bh[((size_t)((wcol*4+ct)*64 + lane))*8];
        f16x8 bl = *(const f16x8*)&Bl[((size_t)((wcol*4+ct)*64 + lane))*8];
        #pragma unroll
        for (int rt=0;rt<4;rt++){
            f32x4 a = acc[rt][ct];
            a = __builtin_amdgcn_mfma_f32_16x16x32_f16(ah[rt], bh, a, 0,0,0);
            a = __builtin_amdgcn_mfma_f32_16x16x32_f16(ah[rt], bl, a, 0,0,0);
            a = __builtin_amdgcn_mfma_f32_16x16x32_f16(al[rt], bh, a, 0,0,0);
            acc[rt][ct] = a;
        }
    }
}

// C128 += A(128xK=128, row-major lda) @ B; bContig: B[c][k] (B^T layout); else B[k][c].
__device__ void gemm_f16_unit(const float* __restrict__ A, int lda,
                              const float* __restrict__ B, int ldb, bool bContig,
                              FragLds& F, f32x4 acc[4][4], int tid){
    int lane = tid & 63, w = tid >> 6, wrow = w>>1, wcol = w&1;
    for (int k0 = 0; k0 < NB; k0 += 32){
        __syncthreads();
        stage_f16(F.Ah, F.Al, A, lda, k0, true, tid);
        stage_f16(F.Bh, F.Bl, B, ldb, k0, bContig, tid);
        __syncthreads();
        mfma_slab_f16(F.Ah, F.Al, F.Bh, F.Bl, wrow, wcol, lane, acc);
    }
}

// D-layout store: row = wrow*64+rt*16+kg*4+r, col = wcol*64+ct*16+fr
__device__ __forceinline__ void store_f16acc(float* __restrict__ Cp, int ldc,
                                             const f32x4 acc[4][4], float sgn, int tid){
    int lane = tid&63, w = tid>>6, wrow = w>>1, wcol = w&1;
    int fr = lane&15, kg = lane>>4;
    #pragma unroll
    for (int rt=0;rt<4;rt++)
      #pragma unroll
      for (int ct=0;ct<4;ct++)
        #pragma unroll
        for (int r=0;r<4;r++){
            int row = wrow*64 + rt*16 + kg*4 + r;
            int col = wcol*64 + ct*16 + fr;
            Cp[(size_t)row*ldc + col] = sgn*acc[rt][ct][r];
        }
}

#define ZERO_ACC(acc) { _Pragma("unroll") for (int zi=0;zi<4;zi++) _Pragma("unroll") for (int zj=0;zj<4;zj++) acc[zi][zj] = (f32x4)0.0f; }

// ---------------- kernels ----------------

__global__ void k_init_acc(float* __restrict__ acc){
    int i = blockIdx.x*blockDim.x + threadIdx.x;
    if (i < 2*M) acc[i] = 0.0f;
}

// d2te[j][i] = ||Xte_j - Xtr_i||^2   (M x N)
__global__ void k_build_d2te(const float* __restrict__ Xtr, const float* __restrict__ Xte,
                             float* __restrict__ d2){
    int j = blockIdx.x;
    float4 xj = ((const float4*)Xte)[j];
    for (int i = threadIdx.x; i < N; i += blockDim.x){
        float4 xi = ((const float4*)Xtr)[i];
        d2[(size_t)j*N + i] = sqdist4(xi,xj);
    }
}

// Build packed lower-tri blocks of K_noisy. grid (NBLK, g)
__global__ __launch_bounds__(256) void k_build_K(const float* __restrict__ Xtr,
                          const float* __restrict__ ls,
                          const float* __restrict__ var, const float* __restrict__ noise,
                          float* __restrict__ Lbuf){
    __shared__ float4 xr[NB], xc[NB];
    int c = blockIdx.y, flat = blockIdx.x;
    int ib = 0; while ((ib+1)*(ib+2)/2 <= flat) ib++;
    int jt = flat - ib*(ib+1)/2;
    int tid = threadIdx.x;
    if (tid < NB) xr[tid] = ((const float4*)Xtr)[ib*NB + tid];
    else          xc[tid-NB] = ((const float4*)Xtr)[jt*NB + (tid-NB)];
    __syncthreads();
    float il2 = 1.0f/(ls[c]*ls[c]);
    float vc = var[c], nc = noise[c];
    float* blk = Lbuf + c*PL + pblk(ib,jt);
    for (int idx = tid; idx < NB*NB; idx += 256){
        int r = idx >> 7, col = idx & 127;
        float d2v = sqdist4(xr[r], xc[col]);
        float v = vc*__expf(-0.5f*d2v*il2);
        if (ib==jt && r==col) v += nc;
        blk[idx] = v;
    }
}

// standalone factor+invert of diag block (0,0)
__global__ __launch_bounds__(256) void k_diagF(float* __restrict__ Lbuf){
    __shared__ float T[NB][NB];
    int c = blockIdx.x, tid = threadIdx.x;
    float* A = Lbuf + c*PL + pblk(0,0);
    for (int idx = tid; idx < NB*NB; idx += 256){
        int r = idx >> 7, col = idx & 127;
        TT(r,col) = A[idx];
    }
    __syncthreads();
    chol_invert_lds(T, tid);
    for (int idx = tid; idx < NB*NB; idx += 256){
        int r = idx >> 7, col = idx & 127;
        A[idx] = (col <= r) ? TT(r,col) : 0.0f;
    }
}

// panel TRSM as GEMM: L[ib,kb] = L[ib,kb] @ Dinv_kb^T   (split-f16 MFMA, in place)
__global__ __launch_bounds__(256) void k_panel(float* __restrict__ Lbuf, int kb){
    __shared__ FragLds F;
    int c = blockIdx.x;
    int ib = kb + 1 + blockIdx.y;
    int tid = threadIdx.x;
    float* base = Lbuf + c*PL;
    float* Ablk = base + pblk(ib,kb);
    const float* Dv = base + pblk(kb,kb);
    f32x4 acc[4][4]; ZERO_ACC(acc);
    gemm_f16_unit(Ablk, NB, Dv, NB, true, F, acc, tid);   // B[c][k]=Dinv[c][k]
    store_f16acc(Ablk, NB, acc, 1.0f, tid);
}

// trailing update K[i,j] -= P_i @ P_j^T; flat==0 block also factors+inverts
union SmU2 { FragLds f; float T[NB][NB]; };   // 64 KiB
__global__ __launch_bounds__(256) void k_syrk(float* __restrict__ Lbuf, int kb){
    __shared__ SmU2 sm;
    int c = blockIdx.x;
    int flat = blockIdx.y;
    int di = 0; while ((di+1)*(di+2)/2 <= flat) di++;
    int dj = flat - di*(di+1)/2;
    int i = kb+1+di, j = kb+1+dj;
    int tid = threadIdx.x;
    float* base = Lbuf + c*PL;
    float* Cblk = base + pblk(i,j);
    const float* Ablk = base + pblk(i,kb);
    const float* Bblk = base + pblk(j,kb);
    f32x4 acc[4][4]; ZERO_ACC(acc);
    gemm_f16_unit(Ablk, NB, Bblk, NB, true, sm.f, acc, tid);  // B[c][k]=L[j,kb][c][k]
    int lane = tid&63, w = tid>>6, wrow = w>>1, wcol = w&1;
    int fr = lane&15, kg = lane>>4;
    if (flat != 0){
        #pragma unroll
        for (int rt=0;rt<4;rt++)
          #pragma unroll
          for (int ct=0;ct<4;ct++)
            #pragma unroll
            for (int r=0;r<4;r++){
                int row = wrow*64 + rt*16 + kg*4 + r;
                int col = wcol*64 + ct*16 + fr;
                Cblk[(size_t)row*NB + col] -= acc[rt][ct][r];
            }
    } else {
        __syncthreads();   // frag LDS reads done; safe to reuse as T
        float (*T)[NB] = sm.T;
        #pragma unroll
        for (int rt=0;rt<4;rt++)
          #pragma unroll
          for (int ct=0;ct<4;ct++)
            #pragma unroll
            for (int r=0;r<4;r++){
                int row = wrow*64 + rt*16 + kg*4 + r;
                int col = wcol*64 + ct*16 + fr;
                TT(row,col) = Cblk[(size_t)row*NB + col] - acc[rt][ct][r];
            }
        __syncthreads();
        chol_invert_lds(T, tid);
        for (int idx = tid; idx < NB*NB; idx += 256){
            int r = idx >> 7, col = idx & 127;
            Cblk[idx] = (col <= r) ? TT(r,col) : 0.0f;
        }
    }
}

// G(ct) = Dinv_ib @ L[ib,ct]   (split-f16 MFMA; writes Trow [NB][N])
__global__ __launch_bounds__(256) void k_gemmA(float* __restrict__ Trow,
                                               const float* __restrict__ Lbuf, int ib){
    __shared__ FragLds F;
    int c = blockIdx.x, ct = blockIdx.y;
    int tid = threadIdx.x;
    const float* base = Lbuf + c*PL;
    const float* Dv = base + pblk(ib,ib);
    const float* Bsrc = base + pblk(ib,ct);
    f32x4 acc[4][4]; ZERO_ACC(acc);
    gemm_f16_unit(Dv, NB, Bsrc, NB, false, F, acc, tid);  // B[k][c] strided
    store_f16acc(Trow + (size_t)c*NB*N + ct*NB, N, acc, 1.0f, tid);
}

// W[ib,jt] = - sum_{kt=jt..ib-1} G[:,kt] @ W[kt,jt]   (split-f16 MFMA)
__global__ __launch_bounds__(256) void k_gemmB(float* __restrict__ Lbuf,
                                               const float* __restrict__ Trow, int ib){
    __shared__ FragLds F;
    int c = blockIdx.x, jt = blockIdx.y;
    int tid = threadIdx.x;
    const float* G = Trow + (size_t)c*NB*N;
    float* base = Lbuf + c*PL;
    f32x4 acc[4][4]; ZERO_ACC(acc);
    for (int kt = jt; kt < ib; kt++)
        gemm_f16_unit(G + kt*NB, N, base + pblk(kt,jt), NB, false, F, acc, tid);
    store_f16acc(base + pblk(ib,jt), NB, acc, -1.0f, tid);
}

// z[c] = W y  (triangular matvec over packed blocks; W still f32 here)
__global__ void k_zvec(const float* __restrict__ Lbuf, const float* __restrict__ y,
                       float* __restrict__ z){
    int c = blockIdx.x;
    int p = blockIdx.y * 4 + (threadIdx.x >> 6);
    int lane = threadIdx.x & 63;
    int pb = p >> 7, pl = p & 127;
    const float* base = Lbuf + c*PL;
    float s = 0.0f;
    for (int kt = 0; kt <= pb; kt++){
        const float* row = base + pblk(pb,kt) + (size_t)pl*NB;
        int lim = (kt==pb) ? pl : NB-1;
        for (int i = lane; i <= lim; i += 64) s += row[i]*y[kt*NB + i];
    }
    for (int off = 32; off; off >>= 1) s += __shfl_down(s, off);
    if (lane == 0) z[c*N + p] = s;
}

// Convert packed W block IN PLACE to fragment-order split-bf16 images.
// Layout per block (as shorts): [slab 0..3][hi/lo][512 units][8 shorts].
// Register-staged: all reads before barrier, all writes after (block-local).
__global__ __launch_bounds__(256) void k_wsplit(float* __restrict__ Lbuf){
    int c = blockIdx.y, flat = blockIdx.x;
    int tid = threadIdx.x;
    float* blk = Lbuf + c*PL + (size_t)flat*NB*NB;
    float4 v[16];
    #pragma unroll
    for (int h = 0; h < 8; h++){
        int g = tid + h*256;           // unit-global 0..2047
        int u = g & 511, slab = g >> 9;
        int fr = u&15, kg = (u>>4)&3, rt = (u>>6)&3, hf = u>>8;
        int row = hf*64 + rt*16 + fr;
        int k = slab*32 + kg*8;
        v[2*h]   = *(const float4*)&blk[(size_t)row*NB + k];
        v[2*h+1] = *(const float4*)&blk[(size_t)row*NB + k + 4];
    }
    __syncthreads();
    unsigned short* out = (unsigned short*)blk;
    #pragma unroll
    for (int h = 0; h < 8; h++){
        int g = tid + h*256;
        int u = g & 511, slab = g >> 9;
        uint2 h0, l0, h1, l1;
        split4(v[2*h].x, v[2*h].y, v[2*h].z, v[2*h].w, h0, l0);
        split4(v[2*h+1].x, v[2*h+1].y, v[2*h+1].z, v[2*h+1].w, h1, l1);
        *(uint4*)&out[((size_t)(slab*2+0)*512 + u)*8] = make_uint4(h0.x,h0.y,h1.x,h1.y);
        *(uint4*)&out[((size_t)(slab*2+1)*512 + u)*8] = make_uint4(l0.x,l0.y,l1.x,l1.y);
    }
}

// Fused A = Kte @ W^T via split-bf16 MFMA.
// A: round-6 global pattern + fragment-order LDS writes. B: direct copy of
// pre-split W images (zero VALU). Rowwise mean/var reduction epilogue.
__global__ __launch_bounds__(256) void k_bigg(const float* __restrict__ Lbuf,
                                              const float* __restrict__ d2,   // [M][N]
                                              const float* __restrict__ zbuf,
                                              const float* __restrict__ ls,
                                              const float* __restrict__ var,
                                              float* __restrict__ acc_out){
    __shared__ unsigned short Ah[4096], Al[4096], Bh[4096], Bl[4096];  // 32 KiB
    int jt = blockIdx.x, pt = blockIdx.y, c = blockIdx.z;
    int tid = threadIdx.x;
    int lane = tid & 63, w = tid >> 6;
    int wrow = w >> 1, wcol = w & 1;
    float il2 = 1.0f/(ls[c]*ls[c]);
    float vc = var[c];
    float ec = -0.5f*il2;
    const float* Arow = d2 + (size_t)(jt*NB)*N;
    const float* Wbase = Lbuf + c*PL;
    int klen = (pt+1)*NB;
    f32x4 acc[4][4]; ZERO_ACC(acc);

    int fr = lane & 15, kg = lane >> 4;
    int q = tid & 7, rs = tid >> 3;          // A staging: q = 16B col-quad, rs = row base
    int kgq = q >> 1, e4 = (q & 1) * 4;      // unit col-group + intra-unit offset

    for (int k0 = 0; k0 < klen; k0 += 32){
        const unsigned short* Wimg = (const unsigned short*)(Wbase + pblk(pt, k0 >> 7));
        int slab = (k0 & 127) >> 5;
        const unsigned short* hi_img = Wimg + (size_t)(slab*2+0)*4096;
        const unsigned short* lo_img = Wimg + (size_t)(slab*2+1)*4096;
        __syncthreads();
        // A tile: contiguous 128B-per-row global reads, frag-order LDS writes
        #pragma unroll
        for (int p = 0; p < 4; p++){
            int row = rs + 32*p;
            float4 dv = *(const float4*)&Arow[(size_t)row*N + k0 + q*4];
            float x0 = vc*__expf(ec*dv.x), x1 = vc*__expf(ec*dv.y);
            float x2 = vc*__expf(ec*dv.z), x3 = vc*__expf(ec*dv.w);
            uint2 hi, lo; split4(x0,x1,x2,x3, hi, lo);
            int u = (row&15) + kgq*16 + ((row>>4)&3)*64 + (row>>6)*256;
            *(uint2*)&Ah[(size_t)u*8 + e4] = hi;
            *(uint2*)&Al[(size_t)u*8 + e4] = lo;
        }
        // B tile: pure 16B copies of pre-split fragment images
        #pragma unroll
        for (int h2 = 0; h2 < 2; h2++){
            int u = tid + h2*256;
            *(uint4*)&Bh[(size_t)u*8] = *(const uint4*)&hi_img[(size_t)u*8];
            *(uint4*)&Bl[(size_t)u*8] = *(const uint4*)&lo_img[(size_t)u*8];
        }
        __syncthreads();
        bf16x8 ah[4], al[4];
        #pragma unroll
        for (int rt=0;rt<4;rt++){
            ah[rt] = *(const bf16x8*)&Ah[((size_t)((wrow*4+rt)*64 + lane))*8];
            al[rt] = *(const bf16x8*)&Al[((size_t)((wrow*4+rt)*64 + lane))*8];
        }
        #pragma unroll
        for (int ct=0;ct<4;ct++){
            bf16x8 bh = *(const bf16x8*)&Bh[((size_t)((wcol*4+ct)*64 + lane))*8];
            bf16x8 bl = *(const bf16x8*)&Bl[((size_t)((wcol*4+ct)*64 + lane))*8];
            #pragma unroll
            for (int rt=0;rt<4;rt++){
                f32x4 a = acc[rt][ct];
                a = __builtin_amdgcn_mfma_f32_16x16x32_bf16(ah[rt], bh, a, 0,0,0);
                a = __builtin_amdgcn_mfma_f32_16x16x32_bf16(ah[rt], bl, a, 0,0,0);
                a = __builtin_amdgcn_mfma_f32_16x16x32_bf16(al[rt], bh, a, 0,0,0);
                acc[rt][ct] = a;
            }
        }
    }
    float zv[4];
    #pragma unroll
    for (int ct=0;ct<4;ct++) zv[ct] = zbuf[c*N + pt*NB + wcol*64 + ct*16 + fr];
    #pragma unroll
    for (int rt=0;rt<4;rt++){
        #pragma unroll
        for (int r=0;r<4;r++){
            float m = 0.0f, v = 0.0f;
            #pragma unroll
            for (int ct=0;ct<4;ct++){
                float x = acc[rt][ct][r];
                v += x*x; m += x*zv[ct];
            }
            m += __shfl_xor(m, 1);  v += __shfl_xor(v, 1);
            m += __shfl_xor(m, 2);  v += __shfl_xor(v, 2);
            m += __shfl_xor(m, 4);  v += __shfl_xor(v, 4);
            m += __shfl_xor(m, 8);  v += __shfl_xor(v, 8);
            if (fr == 0){
                int j = jt*NB + wrow*64 + rt*16 + kg*4 + r;
                atomicAdd(&acc_out[j], m);
                atomicAdd(&acc_out[M + j], v);
            }
        }
    }
}

__global__ void k_final(const float* __restrict__ acc, float* __restrict__ out){
    int i = blockIdx.x*blockDim.x + threadIdx.x;
    if (i < 2*M) out[i] = acc[i] * (1.0f/64.0f);
}

// ---------------- launch ----------------

extern "C" void kernel_launch(void* const* d_in, const int* in_sizes, int n_in,
                              void* d_out, int out_size, void* d_ws, size_t ws_size,
                              hipStream_t stream) {
    const float* Xtr = (const float*)d_in[0];
    const float* ytr = (const float*)d_in[1];
    const float* Xte = (const float*)d_in[2];
    const float* ls  = (const float*)d_in[3];
    const float* var = (const float*)d_in[4];
    const float* noi = (const float*)d_in[5];
    float* out = (float*)d_out;

    float* ws = (float*)d_ws;
    const size_t shared_fl  = (size_t)N*M + 2*M;              // d2te + acc
    const size_t perchain   = PL + (size_t)NB*N + (size_t)N;  // L + Trow + z
    size_t avail = ws_size / sizeof(float);
    if (avail < shared_fl + perchain) return;
    int Gmax = (int)((avail - shared_fl) / perchain);
    if (Gmax > C) Gmax = C;
    int nbatch = (C + Gmax - 1) / Gmax;
    int G = (C + nbatch - 1) / nbatch;          // balanced batches

    float* d2te = ws;
    float* acc  = d2te + (size_t)N*M;
    float* Lbuf = acc  + 2*M;
    float* Trow = Lbuf + (size_t)G*PL;
    float* zbuf = Trow + (size_t)G*NB*N;

    k_init_acc<<<dim3((2*M+255)/256), dim3(256), 0, stream>>>(acc);
    k_build_d2te<<<dim3(M), dim3(256), 0, stream>>>(Xtr, Xte, d2te);

    for (int c0 = 0; c0 < C; c0 += G){
        int g = C - c0 < G ? C - c0 : G;

        k_build_K<<<dim3(NBLK, g), dim3(256), 0, stream>>>(Xtr, ls+c0, var+c0, noi+c0, Lbuf);
        k_diagF<<<dim3(g), dim3(256), 0, stream>>>(Lbuf);

        for (int kb = 0; kb < TB-1; kb++){
            int rem = TB-1-kb;
            k_panel<<<dim3(g, rem), dim3(256), 0, stream>>>(Lbuf, kb);
            k_syrk<<<dim3(g, rem*(rem+1)/2), dim3(256), 0, stream>>>(Lbuf, kb);
        }
        for (int ib = 1; ib < TB; ib++){
            k_gemmA<<<dim3(g, ib), dim3(256), 0, stream>>>(Trow, Lbuf, ib);
            k_gemmB<<<dim3(g, ib), dim3(256), 0, stream>>>(Lbuf, Trow, ib);
        }
        k_zvec<<<dim3(g, N/4), dim3(256), 0, stream>>>(Lbuf, ytr, zbuf);
        k_wsplit<<<dim3(NBLK, g), dim3(256), 0, stream>>>(Lbuf);
        k_bigg<<<dim3(M/NB, TB, g), dim3(256), 0, stream>>>(Lbuf, d2te, zbuf, ls+c0, var+c0, acc);
    }
    k_final<<<dim3((2*M+255)/256), dim3(256), 0, stream>>>(acc, out);
}